// Round 5
// baseline (3927.110 us; speedup 1.0000x reference)
//
#include <hip/hip_runtime.h>
#include <hip/hip_bf16.h>
#include <stdint.h>

// Problem: S=512, N=64, E=256, NH=8, HD=32, LH=512.
// Pipeline: convert -> qkv -> attn -> outproj -> gates GEMM -> persistent LSTM -> final proj.
// R11 = R9 (poison-validated direct h read; proven correct) x R10 (replica L2 flags; proven
// fast) with the lethal parts of each removed:
//  - COMMON PATH: consumer reads its h A-fragments directly (step-fresh addresses -> L1
//    miss -> local XCD L2, R5-proven) and validates poison bits (bit14 of each bf16;
//    real |h| <= 1.0 => bit14==0; poison 0x7F7F has it set; 2B stores are atomic).
//    No flag poll, no poll-syncthreads, no flag RTT on the critical path. Per-WAVE
//    validation (waves sync later at the existing Dg barrier anyway). 2 barriers/step.
//  - RARE PATH (early arrival): confirm via R10 replica flags (fresh-address retries,
//    proven) + IC fallback, then evict stale poison from the 32KB L1 by sweeping 128KB
//    of the gates region (4x capacity; touches ONLY this CU's L1 — NOT the shared L2,
//    which is what made R9's agent-fence a 3x disaster), re-read, re-validate, bounded.
//  - 4 independent MFMA chains (was 2) to halve dependent-MFMA depth.
// Kept: nx prefetch after validation (R7/R8), v_rcp elementwise, producer replica+IC
// flag stores after the h-drain barrier.

typedef __attribute__((ext_vector_type(8))) short bf16x8;
typedef __attribute__((ext_vector_type(4))) float f32x4;
typedef __attribute__((ext_vector_type(4))) unsigned int u32x4;

__device__ __forceinline__ unsigned short f2bf(float f){
  unsigned u = __float_as_uint(f);
  u += 0x7FFFu + ((u >> 16) & 1u);          // RNE
  return (unsigned short)(u >> 16);
}
__device__ __forceinline__ float b2f(unsigned short h){
  return __uint_as_float(((unsigned)h) << 16);
}
__device__ __forceinline__ ushort4 f4tobf(float4 f){
  ushort4 o; o.x=f2bf(f.x); o.y=f2bf(f.y); o.z=f2bf(f.z); o.w=f2bf(f.w); return o;
}

// raw 16B load, volatile so retries re-execute; wait handled by caller.
__device__ __forceinline__ u32x4 ll_b128(const void* p){
  u32x4 v;
  asm volatile("global_load_dwordx4 %0, %1, off" : "=v"(v) : "v"(p) : "memory");
  return v;
}

// ---------------- workspace layout (bytes) ----------------
// flagsIC:  [0x0,      0x4000)   8 groups x 32 slots, 64B stride (IC fallback flags)
// cnt:      [0x4000,   0x4020)   8 ints, per-XCD slot claim
// pooled:   [0x30000,  0x50000)  64x512 f32
// w_ih bf16:[0x50000,  0x250000)
// flr:      [0x300000, 0x700000) replicated L2 flags: [st][r<8][g][slot] int, 4MB
// combined: [0x800000, 0x2800000) 32768x512 bf16; REUSED by k_lstm as h-ring:
//           ring[st][g] = 8KB (8 batches x 512 units bf16), 64KB/step, 32MB total
// gates:    [0x3000000,0xB000000) layout [m][u][gate] = m*2048 + u*4 + gate (aliases q/k/v/ctx)
// q:0x3000000 k:0x4000000 v:0x5000000 ctx:0x6000000 (each 16MB bf16)
// total required ws: 0xB000000 = 184,549,376 B

// K0: w_ih fp32->bf16, and x fp32 -> combined[:, 0:256] bf16
__global__ __launch_bounds__(256) void k_convert(const float* __restrict__ wih,
                                                 const float* __restrict__ x,
                                                 unsigned short* __restrict__ wih_bf,
                                                 unsigned short* __restrict__ comb){
  size_t i = ((size_t)blockIdx.x * 256 + threadIdx.x) * 4;
  if (i < 1048576){
    float4 f = *(const float4*)(wih + i);
    *(ushort4*)(wih_bf + i) = f4tobf(f);
  } else {
    size_t j = i - 1048576;
    if (j < 8388608){
      float4 f = *(const float4*)(x + j);
      size_t m = j >> 8, c = j & 255;
      *(ushort4*)(comb + m*512 + c) = f4tobf(f);
    }
  }
}

// K1: qkv = x @ in_proj_w.T + b ; scale folded into q; writes q/k [n][h][s][d], v transposed [n][h][d][s]
__global__ __launch_bounds__(256) void k_qkv(const unsigned short* __restrict__ xb,
                                             const float* __restrict__ w,
                                             const float* __restrict__ bias,
                                             unsigned short* __restrict__ q,
                                             unsigned short* __restrict__ kk,
                                             unsigned short* __restrict__ v){
  const int nt = blockIdx.x;    // 0..11
  const int mt = blockIdx.y;    // 0..511  (= s, since M-row = s*64+n)
  __shared__ unsigned short Bs[64][264];
  const int t = threadIdx.x;
  { // stage+convert B tile (in_proj_w rows nt*64..+64, k 0..256)
    int row = t >> 2, c0 = (t & 3) * 64;
    const float* src = w + (size_t)(nt*64 + row)*256 + c0;
    #pragma unroll
    for (int i = 0; i < 64; i += 4){
      float4 f = *(const float4*)(src + i);
      *(ushort4*)&Bs[row][c0 + i] = f4tobf(f);
    }
  }
  __syncthreads();
  const int w4 = t >> 6, l = t & 63, lr = l & 15, lc = l >> 4;
  f32x4 acc[4];
  #pragma unroll
  for (int i = 0; i < 4; ++i) acc[i] = (f32x4){0.f,0.f,0.f,0.f};
  const size_t arow = (size_t)(mt*64 + w4*16 + lr) * 512;  // A from combined (bf16 x)
  #pragma unroll
  for (int kt = 0; kt < 8; ++kt){
    bf16x8 a = *(const bf16x8*)(xb + arow + kt*32 + lc*8);
    #pragma unroll
    for (int n4 = 0; n4 < 4; ++n4){
      bf16x8 b = *(const bf16x8*)&Bs[n4*16 + lr][kt*32 + lc*8];
      acc[n4] = __builtin_amdgcn_mfma_f32_16x16x32_bf16(a, b, acc[n4], 0, 0, 0);
    }
  }
  const int s = mt;
  #pragma unroll
  for (int n4 = 0; n4 < 4; ++n4){
    int ncol = nt*64 + n4*16 + lr;
    float bv = bias[ncol];
    int which = ncol >> 8, rem = ncol & 255, hh = rem >> 5, d = rem & 31;
    #pragma unroll
    for (int reg = 0; reg < 4; ++reg){
      int nb = w4*16 + lc*4 + reg;   // batch
      float val = acc[n4][reg] + bv;
      if (which == 0){
        val *= 0.17677669529663687f;  // 1/sqrt(32)
        q[((size_t)(nb*8 + hh)*512 + s)*32 + d] = f2bf(val);
      } else if (which == 1){
        kk[((size_t)(nb*8 + hh)*512 + s)*32 + d] = f2bf(val);
      } else {
        v[((size_t)(nb*8 + hh)*32 + d)*512 + s] = f2bf(val);
      }
    }
  }
}

// K2: attention for one (n,h); Q-tile=32, full-S bf16 score strip in LDS, exp recomputed into PV A-frags
__global__ __launch_bounds__(256) void k_attn(const unsigned short* __restrict__ q,
                                              const unsigned short* __restrict__ k,
                                              const unsigned short* __restrict__ v,
                                              unsigned short* __restrict__ ctx){
  const int nh = blockIdx.x;
  const int n = nh >> 3, h = nh & 7;
  __shared__ unsigned short sc[32][520];
  __shared__ float red[32][8];
  __shared__ float rowmax[32], rowinv[32];
  const unsigned short* qb = q + (size_t)nh * 512 * 32;
  const unsigned short* kb = k + (size_t)nh * 512 * 32;
  const unsigned short* vb = v + (size_t)nh * 32 * 512;
  const int t = threadIdx.x, w4 = t >> 6, l = t & 63, lr = l & 15, lc = l >> 4;
  const int r = t >> 3, cc = t & 7;
  for (int qt = 0; qt < 16; ++qt){
    const int s0 = qt * 32;
    bf16x8 aq0 = *(const bf16x8*)(qb + (size_t)(s0 + lr)*32 + lc*8);
    bf16x8 aq1 = *(const bf16x8*)(qb + (size_t)(s0 + 16 + lr)*32 + lc*8);
    #pragma unroll
    for (int j = 0; j < 8; ++j){
      int ntl = w4*8 + j;
      bf16x8 bk = *(const bf16x8*)(kb + (size_t)(ntl*16 + lr)*32 + lc*8);
      f32x4 d0 = (f32x4){0.f,0.f,0.f,0.f}, d1 = (f32x4){0.f,0.f,0.f,0.f};
      d0 = __builtin_amdgcn_mfma_f32_16x16x32_bf16(aq0, bk, d0, 0, 0, 0);
      d1 = __builtin_amdgcn_mfma_f32_16x16x32_bf16(aq1, bk, d1, 0, 0, 0);
      #pragma unroll
      for (int reg = 0; reg < 4; ++reg){
        sc[lc*4 + reg][ntl*16 + lr]      = f2bf(d0[reg]);
        sc[16 + lc*4 + reg][ntl*16 + lr] = f2bf(d1[reg]);
      }
    }
    __syncthreads();
    float pm = -1e30f;
    for (int i = 0; i < 64; ++i) pm = fmaxf(pm, b2f(sc[r][cc + 8*i]));
    red[r][cc] = pm;
    __syncthreads();
    float mfull = red[r][0];
    #pragma unroll
    for (int i = 1; i < 8; ++i) mfull = fmaxf(mfull, red[r][i]);
    rowmax[r] = mfull;   // benign same-value race across the 8 threads of a row
    __syncthreads();
    float sum = 0.f;
    for (int i = 0; i < 64; ++i) sum += __expf(b2f(sc[r][cc + 8*i]) - mfull);
    red[r][cc] = sum;
    __syncthreads();
    float ss = 0.f;
    #pragma unroll
    for (int i = 0; i < 8; ++i) ss += red[r][i];
    rowinv[r] = 1.f / ss;
    __syncthreads();
    // PV: each wave one 16x16 tile of the 32x32 O
    const int mt = w4 >> 1, ntd = w4 & 1;
    const int arow = mt*16 + lr;
    const float mrow = rowmax[arow];
    f32x4 o = (f32x4){0.f,0.f,0.f,0.f};
    for (int kt = 0; kt < 16; ++kt){
      bf16x8 sv = *(const bf16x8*)&sc[arow][kt*32 + lc*8];
      bf16x8 ap;
      #pragma unroll
      for (int e = 0; e < 8; ++e){
        float p = __expf(b2f((unsigned short)sv[e]) - mrow);
        ap[e] = (short)f2bf(p);
      }
      bf16x8 bv = *(const bf16x8*)(vb + (size_t)(ntd*16 + lr)*512 + kt*32 + lc*8);
      o = __builtin_amdgcn_mfma_f32_16x16x32_bf16(ap, bv, o, 0, 0, 0);
    }
    #pragma unroll
    for (int reg = 0; reg < 4; ++reg){
      int row = mt*16 + lc*4 + reg;
      int d = ntd*16 + lr;
      float val = o[reg] * rowinv[row];
      ctx[((size_t)(s0 + row)*64 + n)*256 + h*32 + d] = f2bf(val);
    }
    __syncthreads();
  }
}

// K3: attn_out = ctx @ mha_out_w.T + b -> combined[:, 256:512]
__global__ __launch_bounds__(256) void k_outproj(const unsigned short* __restrict__ ctx,
                                                 const float* __restrict__ w,
                                                 const float* __restrict__ bias,
                                                 unsigned short* __restrict__ comb){
  const int nt = blockIdx.x;   // 0..3
  const int mt = blockIdx.y;   // 0..511
  __shared__ unsigned short Bs[64][264];
  const int t = threadIdx.x;
  {
    int row = t >> 2, c0 = (t & 3) * 64;
    const float* src = w + (size_t)(nt*64 + row)*256 + c0;
    #pragma unroll
    for (int i = 0; i < 64; i += 4){
      float4 f = *(const float4*)(src + i);
      *(ushort4*)&Bs[row][c0 + i] = f4tobf(f);
    }
  }
  __syncthreads();
  const int w4 = t >> 6, l = t & 63, lr = l & 15, lc = l >> 4;
  f32x4 acc[4];
  #pragma unroll
  for (int i = 0; i < 4; ++i) acc[i] = (f32x4){0.f,0.f,0.f,0.f};
  const size_t arow = (size_t)(mt*64 + w4*16 + lr) * 256;
  #pragma unroll
  for (int kt = 0; kt < 8; ++kt){
    bf16x8 a = *(const bf16x8*)(ctx + arow + kt*32 + lc*8);
    #pragma unroll
    for (int n4 = 0; n4 < 4; ++n4){
      bf16x8 b = *(const bf16x8*)&Bs[n4*16 + lr][kt*32 + lc*8];
      acc[n4] = __builtin_amdgcn_mfma_f32_16x16x32_bf16(a, b, acc[n4], 0, 0, 0);
    }
  }
  #pragma unroll
  for (int n4 = 0; n4 < 4; ++n4){
    int ncol = nt*64 + n4*16 + lr;
    float bv = bias[ncol];
    #pragma unroll
    for (int reg = 0; reg < 4; ++reg){
      int m = mt*64 + w4*16 + lc*4 + reg;
      comb[(size_t)m*512 + 256 + ncol] = f2bf(acc[n4][reg] + bv);
    }
  }
}

// K4: gates_x = combined @ w_ih.T + (b_ih + b_hh), 128x128 tiles, BK=64.
// Output layout for k_lstm: gates[m][u][gate] = m*2048 + u*4 + gate  (m = st*64 + n).
__global__ __launch_bounds__(256) void k_gates(const unsigned short* __restrict__ A,
                                               const unsigned short* __restrict__ B,
                                               const float* __restrict__ bih,
                                               const float* __restrict__ bhh,
                                               unsigned short* __restrict__ gates){
  const int ntile = blockIdx.x;  // 0..15
  const int mtile = blockIdx.y;  // 0..255
  __shared__ unsigned short As[128][72], Bss[128][72];
  const int t = threadIdx.x, w4 = t >> 6, l = t & 63, lr = l & 15, lc = l >> 4;
  const int wm = w4 >> 1, wn = w4 & 1;
  f32x4 acc[4][4];
  #pragma unroll
  for (int i = 0; i < 4; ++i)
    #pragma unroll
    for (int j = 0; j < 4; ++j) acc[i][j] = (f32x4){0.f,0.f,0.f,0.f};
  const int srow = t >> 1, half = t & 1;
  const unsigned short* sa = A + (size_t)(mtile*128 + srow)*512 + half*32;
  const unsigned short* sb = B + (size_t)(ntile*128 + srow)*512 + half*32;
  for (int kkk = 0; kkk < 8; ++kkk){
    #pragma unroll
    for (int i = 0; i < 4; ++i){
      *(uint4*)&As [srow][half*32 + i*8] = *(const uint4*)(sa + kkk*64 + i*8);
      *(uint4*)&Bss[srow][half*32 + i*8] = *(const uint4*)(sb + kkk*64 + i*8);
    }
    __syncthreads();
    #pragma unroll
    for (int kt = 0; kt < 2; ++kt){
      bf16x8 af[4], bfr[4];
      #pragma unroll
      for (int i = 0; i < 4; ++i) af[i]  = *(const bf16x8*)&As [wm*64 + i*16 + lr][kt*32 + lc*8];
      #pragma unroll
      for (int i = 0; i < 4; ++i) bfr[i] = *(const bf16x8*)&Bss[wn*64 + i*16 + lr][kt*32 + lc*8];
      #pragma unroll
      for (int i = 0; i < 4; ++i)
        #pragma unroll
        for (int j = 0; j < 4; ++j)
          acc[i][j] = __builtin_amdgcn_mfma_f32_16x16x32_bf16(af[i], bfr[j], acc[i][j], 0, 0, 0);
    }
    __syncthreads();
  }
  #pragma unroll
  for (int i = 0; i < 4; ++i){
    #pragma unroll
    for (int j = 0; j < 4; ++j){
      int ncol = ntile*128 + wn*64 + j*16 + lr;
      int gate = ncol >> 9, u = ncol & 511;
      float bsum = bih[ncol] + bhh[ncol];
      #pragma unroll
      for (int reg = 0; reg < 4; ++reg){
        int m = mtile*128 + wm*64 + i*16 + lc*4 + reg;
        gates[(size_t)m*2048 + u*4 + gate] = f2bf(acc[i][j][reg] + bsum);
      }
    }
  }
}

// K5: persistent LSTM, XCD-local. Launch 512 WGs; 86KB LDS -> 1 WG/CU, 32/XCD.
// Claim: g = physical XCC_ID, slot = atomicAdd(cnt[g]); slot>=32 -> exit.
// Handshake: optimistic poison-validated direct read; replica flags + IC + L1-sweep rare path.
__global__ __launch_bounds__(256, 1) void k_lstm(const float* __restrict__ whh,
                                                 const unsigned short* __restrict__ gates,
                                                 unsigned short* __restrict__ ring,
                                                 float* __restrict__ pooled,
                                                 int* __restrict__ flagsIC,
                                                 int* __restrict__ flr,
                                                 int* __restrict__ cnt){
  __shared__ unsigned short Wl[64][512];   // 64KB: rows = gate*16+unit
  __shared__ f32x4 Dg[4*2*16];             // 2KB:  [gate][lc][unit]
  __shared__ float padlds[5120];           // 20KB pad -> 86KB total -> 1 WG/CU
  __shared__ int s_hdr[2];
  const int t = threadIdx.x, w4 = t >> 6, l = t & 63, lr = l & 15, lc = l >> 4;
  if ((int)blockIdx.x == -1) ((volatile float*)padlds)[0] = 1.f;  // keep padlds
  if (t == 0){
    unsigned xcc;
    asm volatile("s_getreg_b32 %0, hwreg(HW_REG_XCC_ID)" : "=s"(xcc));
    int g = (int)(xcc & 7);
    s_hdr[0] = g;
    s_hdr[1] = atomicAdd(&cnt[g], 1);      // device-scope claim
  }
  __syncthreads();
  const int g = s_hdr[0], slot = s_hdr[1];
  if (slot >= 32) return;                  // spare WG: free the CU immediately
  const int j0 = slot * 16;
  { // stage w_hh slice fp32->bf16, chunk swizzle phys = logical ^ (row&7)
    const int row = t >> 2;
    const int gate = row >> 4, u = row & 15;
    const float* src = whh + (size_t)(gate*512 + j0 + u) * 512;
    const int cbase = (t & 3) * 16;
    #pragma unroll
    for (int i = 0; i < 16; ++i){
      const int lch = cbase + i;
      float4 f0 = *(const float4*)(src + lch*8);
      float4 f1 = *(const float4*)(src + lch*8 + 4);
      const int pch = lch ^ (row & 7);
      *(ushort4*)&Wl[row][pch*8]     = f4tobf(f0);
      *(ushort4*)&Wl[row][pch*8 + 4] = f4tobf(f1);
    }
  }
  const int eb = t >> 4, eu = t & 15;      // elementwise ownership, t<128: (batch, unit)
  float cst = 0.f, pool = 0.f;
  unsigned long long gx = 0, nx = 0;
  if (t < 128)
    gx = *(const unsigned long long*)(gates + (size_t)(g*8 + eb)*2048 + (j0 + eu)*4);
  int* const myflagIC = &flagsIC[(g*32 + slot)*16];
  __syncthreads();
  for (int st = 0; st < 512; ++st){
    // ---- optimistic validated read of h(st) A-fragments (8 batches x 512 units) ----
    // Step-fresh addresses: first touch -> L1 miss -> local XCD L2 (peers' plain
    // write-through h stores land there; R5-proven). Poison = bit14 set in any bf16.
    const unsigned short* ha = ring + (((size_t)st*8 + g) << 12) + (lr & 7)*512 + lc*8;
    u32x4 a[16];
    #pragma unroll
    for (int kt = 0; kt < 16; ++kt) a[kt] = ll_b128(ha + kt*32);
    asm volatile("s_waitcnt vmcnt(0)" ::: "memory");
    __builtin_amdgcn_sched_barrier(0);
    unsigned bb = 0;
    #pragma unroll
    for (int kt = 0; kt < 16; ++kt) bb |= a[kt].x | a[kt].y | a[kt].z | a[kt].w;
    if (__any((bb & 0x40004000u) != 0u)){
      // ---- RARE PATH: arrived before peers' h stores drained to L2 ----
      int rep = 0;
      for (int it = 0; it < 256; ++it){
        // 1) confirm all 32 slots done with step st: replica flags (fresh-address
        //    retries, R10-proven), then IC fallback (session-proven, bounded).
        bool ok = false;
        #pragma unroll 1
        while (rep < 8 && !ok){
          int v = ((volatile const int*)flr)[((st*8 + rep)*8 + g)*32 + (l & 31)];
          ok = !__any(v == 0);
          ++rep;
        }
        if (!ok){
          int* fp = &flagsIC[(g*32 + (l & 31))*16];
          int t2 = 0;
          while (__hip_atomic_load(fp, __ATOMIC_RELAXED, __HIP_MEMORY_SCOPE_AGENT) < st
                 && ++t2 < 20000) { }
        }
        // 2) evict stale poison lines from this CU's 32KB L1: sweep 128KB of the
        //    gates region at 64B-line granularity (4x capacity). L2 untouched.
        {
          u32x4 sink = (u32x4){0,0,0,0};
          #pragma unroll
          for (int s2 = 0; s2 < 32; ++s2){
            u32x4 z = ll_b128((const uint8_t*)gates + (size_t)l*64 + (size_t)s2*4096);
            sink.x ^= z.x;
          }
          asm volatile("s_waitcnt vmcnt(0)" ::: "memory");
          asm volatile("" :: "v"(sink.x));   // keep sweep live
        }
        // 3) re-read + re-validate
        #pragma unroll
        for (int kt = 0; kt < 16; ++kt) a[kt] = ll_b128(ha + kt*32);
        asm volatile("s_waitcnt vmcnt(0)" ::: "memory");
        __builtin_amdgcn_sched_barrier(0);
        bb = 0;
        #pragma unroll
        for (int kt = 0; kt < 16; ++kt) bb |= a[kt].x | a[kt].y | a[kt].z | a[kt].w;
        if (!__any((bb & 0x40004000u) != 0u)) break;
      }
    }
    // nx gates HBM prefetch: post-validation, consumed next elementwise (~1500cy slack)
    if (st < 511 && t < 128)
      nx = *(const unsigned long long*)(gates + ((size_t)(st+1)*64 + g*8 + eb)*2048 + (j0 + eu)*4);
    // h(st) @ Wl^T : A rows = 8 batches (lr&7, duplicated), wave w4 = gate w4.
    // 4 independent accumulator chains (dependent-MFMA depth 4).
    f32x4 ac0 = (f32x4){0.f,0.f,0.f,0.f}, ac1 = (f32x4){0.f,0.f,0.f,0.f};
    f32x4 ac2 = (f32x4){0.f,0.f,0.f,0.f}, ac3 = (f32x4){0.f,0.f,0.f,0.f};
    #pragma unroll
    for (int kt = 0; kt < 16; kt += 4){
      bf16x8 b0 = *(const bf16x8*)&Wl[w4*16 + lr][(((kt  )*4 + lc) ^ (lr & 7)) * 8];
      bf16x8 b1 = *(const bf16x8*)&Wl[w4*16 + lr][(((kt+1)*4 + lc) ^ (lr & 7)) * 8];
      bf16x8 b2 = *(const bf16x8*)&Wl[w4*16 + lr][(((kt+2)*4 + lc) ^ (lr & 7)) * 8];
      bf16x8 b3 = *(const bf16x8*)&Wl[w4*16 + lr][(((kt+3)*4 + lc) ^ (lr & 7)) * 8];
      ac0 = __builtin_amdgcn_mfma_f32_16x16x32_bf16(__builtin_bit_cast(bf16x8, a[kt  ]), b0, ac0, 0, 0, 0);
      ac1 = __builtin_amdgcn_mfma_f32_16x16x32_bf16(__builtin_bit_cast(bf16x8, a[kt+1]), b1, ac1, 0, 0, 0);
      ac2 = __builtin_amdgcn_mfma_f32_16x16x32_bf16(__builtin_bit_cast(bf16x8, a[kt+2]), b2, ac2, 0, 0, 0);
      ac3 = __builtin_amdgcn_mfma_f32_16x16x32_bf16(__builtin_bit_cast(bf16x8, a[kt+3]), b3, ac3, 0, 0, 0);
    }
    f32x4 acc = (ac0 + ac1) + (ac2 + ac3);
    if (lc < 2) Dg[(w4*2 + lc)*16 + lr] = acc;   // D: col=unit(lane&15), row=batch(lc*4+reg)
    __syncthreads();
    if (t < 128){
      union { unsigned long long q; unsigned short u[4]; } ga; ga.q = gx;
      const int dq = (eb >> 2)*16 + eu, dr = eb & 3;
      float gi = Dg[0*32 + dq][dr] + b2f(ga.u[0]);
      float gf = Dg[1*32 + dq][dr] + b2f(ga.u[1]);
      float gc = Dg[2*32 + dq][dr] + b2f(ga.u[2]);
      float go = Dg[3*32 + dq][dr] + b2f(ga.u[3]);
      float i_ = __builtin_amdgcn_rcpf(1.f + __expf(-gi));
      float f_ = __builtin_amdgcn_rcpf(1.f + __expf(-gf));
      float cg = fminf(fmaxf(gc, -20.f), 20.f);
      float e2 = __expf(2.f * cg);
      float g_ = 1.f - 2.f * __builtin_amdgcn_rcpf(e2 + 1.f);
      float o_ = __builtin_amdgcn_rcpf(1.f + __expf(-go));
      float cn = f_ * cst + i_ * g_;
      cst = cn;
      float ct = fminf(fmaxf(cn, -20.f), 20.f);
      float e2c = __expf(2.f * ct);
      float th = 1.f - 2.f * __builtin_amdgcn_rcpf(e2c + 1.f);
      float hh = o_ * th;
      pool += hh;
      if (st < 511)  // plain write-through store -> lands in this XCD's L2; |hh|<1 passes validation
        ring[(((size_t)(st+1)*8 + g) << 12) + eb*512 + j0 + eu] = f2bf(hh);
      gx = nx;
    }
    __syncthreads();   // pre-barrier vmcnt(0) drains h stores to L2 [m97-measured semantics]
    if (st < 511){
      // h(st+1) in L2 now. Rare-path oracle: 8 write-once L2 replicas + 1 IC flag.
      if (t < 8) flr[(((st+1)*8 + t)*8 + g)*32 + slot] = 1;
      if (t == 0) __hip_atomic_store(myflagIC, st + 1, __ATOMIC_RELAXED, __HIP_MEMORY_SCOPE_AGENT);
    }
  }
  if (t < 128)
    pooled[(size_t)(g*8 + eb)*512 + j0 + eu] = pool * (1.f / 512.f);
}

// K6: out = log_sigmoid(pooled @ proj_w.T + proj_b)
__global__ __launch_bounds__(256) void k_final(const float* __restrict__ pooled,
                                               const float* __restrict__ w,
                                               const float* __restrict__ bias,
                                               float* __restrict__ out){
  const int n = blockIdx.x;
  __shared__ float pr[512];
  const int t = threadIdx.x;
  pr[t]       = pooled[(size_t)n*512 + t];
  pr[t + 256] = pooled[(size_t)n*512 + t + 256];
  __syncthreads();
  const float* wr = w + (size_t)t * 512;
  float s = bias[t];
  for (int i = 0; i < 512; i += 4){
    float4 f = *(const float4*)(wr + i);
    s += f.x*pr[i] + f.y*pr[i+1] + f.z*pr[i+2] + f.w*pr[i+3];
  }
  float rres = fminf(s, 0.f) - log1pf(__expf(-fabsf(s)));
  out[(size_t)n*256 + t] = rres;
}

extern "C" void kernel_launch(void* const* d_in, const int* in_sizes, int n_in,
                              void* d_out, int out_size, void* d_ws, size_t ws_size,
                              hipStream_t stream){
  const float* x      = (const float*)d_in[0];
  const float* in_w   = (const float*)d_in[1];
  const float* in_b   = (const float*)d_in[2];
  const float* mo_w   = (const float*)d_in[3];
  const float* mo_b   = (const float*)d_in[4];
  const float* w_ih   = (const float*)d_in[5];
  const float* w_hh   = (const float*)d_in[6];
  const float* b_ih   = (const float*)d_in[7];
  const float* b_hh   = (const float*)d_in[8];
  const float* proj_w = (const float*)d_in[9];
  const float* proj_b = (const float*)d_in[10];
  uint8_t* ws = (uint8_t*)d_ws;
  int*            flagsIC = (int*)(ws + 0x0);
  int*            cnt     = (int*)(ws + 0x4000);
  float*          pooled  = (float*)(ws + 0x30000);
  unsigned short* wihbf   = (unsigned short*)(ws + 0x50000);
  int*            flr     = (int*)(ws + 0x300000);
  unsigned short* comb    = (unsigned short*)(ws + 0x800000);  // doubles as h-ring in k_lstm
  unsigned short* gates   = (unsigned short*)(ws + 0x3000000);
  unsigned short* qbuf    = (unsigned short*)(ws + 0x3000000); // aliases gates (dead before k_gates)
  unsigned short* kbuf    = (unsigned short*)(ws + 0x4000000);
  unsigned short* vbuf    = (unsigned short*)(ws + 0x5000000);
  unsigned short* ctx     = (unsigned short*)(ws + 0x6000000);

  hipMemsetAsync(ws + 0x300000, 0, 0x400000, stream);  // flr
  hipMemsetAsync(ws, 0, 0x4020, stream);               // flagsIC + cnt
  hipLaunchKernelGGL(k_convert, dim3(9216),    dim3(256), 0, stream, w_ih, x, wihbf, comb);
  hipLaunchKernelGGL(k_qkv,     dim3(12, 512), dim3(256), 0, stream, comb, in_w, in_b, qbuf, kbuf, vbuf);
  hipLaunchKernelGGL(k_attn,    dim3(512),     dim3(256), 0, stream, qbuf, kbuf, vbuf, ctx);
  hipLaunchKernelGGL(k_outproj, dim3(4, 512),  dim3(256), 0, stream, ctx, mo_w, mo_b, comb);
  hipLaunchKernelGGL(k_gates,   dim3(16, 256), dim3(256), 0, stream, comb, wihbf, b_ih, b_hh, gates);
  // comb dead now: poison the whole h-ring (bit14-set bf16 everywhere), then zero slot 0
  // (= h(-1) = 0, passes validation). Kernel-boundary cache maintenance publishes both.
  hipMemsetAsync(comb, 0x7F, 0x2000000, stream);
  hipMemsetAsync(comb, 0, 0x10000, stream);
  hipLaunchKernelGGL(k_lstm,    dim3(512),     dim3(256), 0, stream, w_hh, gates, comb, pooled, flagsIC, flr, cnt);
  hipLaunchKernelGGL(k_final,   dim3(64),      dim3(256), 0, stream, pooled, proj_w, proj_b, (float*)d_out);
}

// Round 6
// 2159.265 us; speedup vs baseline: 1.8187x; 1.8187x over previous
//
#include <hip/hip_runtime.h>
#include <hip/hip_bf16.h>
#include <stdint.h>

// Problem: S=512, N=64, E=256, NH=8, HD=32, LH=512.
// Pipeline: convert -> qkv -> attn -> outproj -> gates GEMM -> persistent LSTM -> final proj.
// R12 = R10 (proven flag-then-read) restructured to HIDE the handshake:
//  - R11's lesson: consumers are SYSTEMATICALLY ~1 store-drain early; optimistic reads
//    always fail. The wait must exist; make it overlap producer tails instead of serializing.
//  - Role split: waves 2-3 poll global wave-flags for step st while waves 0-1 (same WG)
//    are still in elementwise(st-1)+stores; on success publish to LDS s_ready (CU-local,
//    ~30cy spin for waves 0-1). Global flag RTT leaves waves 0-1's critical path.
//  - Wave-level early flags: producer waves 0-1 drain their OWN stores (per-wave
//    s_waitcnt vmcnt(0), no barrier) then publish per-wave flags: 64 flags/XCD = one per
//    consumer lane -> single flag load per poll try. 4 fresh-address flr replicas
//    (R10-proven primitive) + IC __hip_atomic fallback (session-proven, bounded).
//  - ONE barrier/step (was 3): Dg double-buffered by st&1; the mid barrier provides all
//    ordering (wave-2 Dg[p] write at st is after barrier_mid(st-1), entered by waves 0-1
//    only after their Dg[p] read at st-2).
//  - Flag-implies-h invariant kept: per-wave vmcnt(0) drain precedes that wave's flag
//    stores; flr is a plain store to the same local L2 the h stores land in.
// Kept: areg burst + 4 MFMA chains, nx prefetch post-gate, v_rcp elementwise.

typedef __attribute__((ext_vector_type(8))) short bf16x8;
typedef __attribute__((ext_vector_type(4))) float f32x4;

__device__ __forceinline__ unsigned short f2bf(float f){
  unsigned u = __float_as_uint(f);
  u += 0x7FFFu + ((u >> 16) & 1u);          // RNE
  return (unsigned short)(u >> 16);
}
__device__ __forceinline__ float b2f(unsigned short h){
  return __uint_as_float(((unsigned)h) << 16);
}
__device__ __forceinline__ ushort4 f4tobf(float4 f){
  ushort4 o; o.x=f2bf(f.x); o.y=f2bf(f.y); o.z=f2bf(f.z); o.w=f2bf(f.w); return o;
}

// ---------------- workspace layout (bytes) ----------------
// flagsIC:  [0x0,      0x4000)   8 groups x 64 wave-slots, 32B stride (IC fallback)
// cnt:      [0x4000,   0x4020)   8 ints, per-XCD slot claim
// pooled:   [0x30000,  0x50000)  64x512 f32
// w_ih bf16:[0x50000,  0x250000)
// flr:      [0x300000, 0x700000) wave-level L2 flags: [st][r<4][g][64] int, 4MB exactly
// combined: [0x800000, 0x2800000) 32768x512 bf16; REUSED by k_lstm as h-ring:
//           ring[st][g] = 8KB (8 batches x 512 units bf16), 64KB/step, 32MB total
// gates:    [0x3000000,0xB000000) layout [m][u][gate] = m*2048 + u*4 + gate (aliases q/k/v/ctx)
// q:0x3000000 k:0x4000000 v:0x5000000 ctx:0x6000000 (each 16MB bf16)
// total required ws: 0xB000000 = 184,549,376 B

// K0: w_ih fp32->bf16, and x fp32 -> combined[:, 0:256] bf16
__global__ __launch_bounds__(256) void k_convert(const float* __restrict__ wih,
                                                 const float* __restrict__ x,
                                                 unsigned short* __restrict__ wih_bf,
                                                 unsigned short* __restrict__ comb){
  size_t i = ((size_t)blockIdx.x * 256 + threadIdx.x) * 4;
  if (i < 1048576){
    float4 f = *(const float4*)(wih + i);
    *(ushort4*)(wih_bf + i) = f4tobf(f);
  } else {
    size_t j = i - 1048576;
    if (j < 8388608){
      float4 f = *(const float4*)(x + j);
      size_t m = j >> 8, c = j & 255;
      *(ushort4*)(comb + m*512 + c) = f4tobf(f);
    }
  }
}

// K1: qkv = x @ in_proj_w.T + b ; scale folded into q; writes q/k [n][h][s][d], v transposed [n][h][d][s]
__global__ __launch_bounds__(256) void k_qkv(const unsigned short* __restrict__ xb,
                                             const float* __restrict__ w,
                                             const float* __restrict__ bias,
                                             unsigned short* __restrict__ q,
                                             unsigned short* __restrict__ kk,
                                             unsigned short* __restrict__ v){
  const int nt = blockIdx.x;    // 0..11
  const int mt = blockIdx.y;    // 0..511  (= s, since M-row = s*64+n)
  __shared__ unsigned short Bs[64][264];
  const int t = threadIdx.x;
  { // stage+convert B tile (in_proj_w rows nt*64..+64, k 0..256)
    int row = t >> 2, c0 = (t & 3) * 64;
    const float* src = w + (size_t)(nt*64 + row)*256 + c0;
    #pragma unroll
    for (int i = 0; i < 64; i += 4){
      float4 f = *(const float4*)(src + i);
      *(ushort4*)&Bs[row][c0 + i] = f4tobf(f);
    }
  }
  __syncthreads();
  const int w4 = t >> 6, l = t & 63, lr = l & 15, lc = l >> 4;
  f32x4 acc[4];
  #pragma unroll
  for (int i = 0; i < 4; ++i) acc[i] = (f32x4){0.f,0.f,0.f,0.f};
  const size_t arow = (size_t)(mt*64 + w4*16 + lr) * 512;  // A from combined (bf16 x)
  #pragma unroll
  for (int kt = 0; kt < 8; ++kt){
    bf16x8 a = *(const bf16x8*)(xb + arow + kt*32 + lc*8);
    #pragma unroll
    for (int n4 = 0; n4 < 4; ++n4){
      bf16x8 b = *(const bf16x8*)&Bs[n4*16 + lr][kt*32 + lc*8];
      acc[n4] = __builtin_amdgcn_mfma_f32_16x16x32_bf16(a, b, acc[n4], 0, 0, 0);
    }
  }
  const int s = mt;
  #pragma unroll
  for (int n4 = 0; n4 < 4; ++n4){
    int ncol = nt*64 + n4*16 + lr;
    float bv = bias[ncol];
    int which = ncol >> 8, rem = ncol & 255, hh = rem >> 5, d = rem & 31;
    #pragma unroll
    for (int reg = 0; reg < 4; ++reg){
      int nb = w4*16 + lc*4 + reg;   // batch
      float val = acc[n4][reg] + bv;
      if (which == 0){
        val *= 0.17677669529663687f;  // 1/sqrt(32)
        q[((size_t)(nb*8 + hh)*512 + s)*32 + d] = f2bf(val);
      } else if (which == 1){
        kk[((size_t)(nb*8 + hh)*512 + s)*32 + d] = f2bf(val);
      } else {
        v[((size_t)(nb*8 + hh)*32 + d)*512 + s] = f2bf(val);
      }
    }
  }
}

// K2: attention for one (n,h); Q-tile=32, full-S bf16 score strip in LDS, exp recomputed into PV A-frags
__global__ __launch_bounds__(256) void k_attn(const unsigned short* __restrict__ q,
                                              const unsigned short* __restrict__ k,
                                              const unsigned short* __restrict__ v,
                                              unsigned short* __restrict__ ctx){
  const int nh = blockIdx.x;
  const int n = nh >> 3, h = nh & 7;
  __shared__ unsigned short sc[32][520];
  __shared__ float red[32][8];
  __shared__ float rowmax[32], rowinv[32];
  const unsigned short* qb = q + (size_t)nh * 512 * 32;
  const unsigned short* kb = k + (size_t)nh * 512 * 32;
  const unsigned short* vb = v + (size_t)nh * 32 * 512;
  const int t = threadIdx.x, w4 = t >> 6, l = t & 63, lr = l & 15, lc = l >> 4;
  const int r = t >> 3, cc = t & 7;
  for (int qt = 0; qt < 16; ++qt){
    const int s0 = qt * 32;
    bf16x8 aq0 = *(const bf16x8*)(qb + (size_t)(s0 + lr)*32 + lc*8);
    bf16x8 aq1 = *(const bf16x8*)(qb + (size_t)(s0 + 16 + lr)*32 + lc*8);
    #pragma unroll
    for (int j = 0; j < 8; ++j){
      int ntl = w4*8 + j;
      bf16x8 bk = *(const bf16x8*)(kb + (size_t)(ntl*16 + lr)*32 + lc*8);
      f32x4 d0 = (f32x4){0.f,0.f,0.f,0.f}, d1 = (f32x4){0.f,0.f,0.f,0.f};
      d0 = __builtin_amdgcn_mfma_f32_16x16x32_bf16(aq0, bk, d0, 0, 0, 0);
      d1 = __builtin_amdgcn_mfma_f32_16x16x32_bf16(aq1, bk, d1, 0, 0, 0);
      #pragma unroll
      for (int reg = 0; reg < 4; ++reg){
        sc[lc*4 + reg][ntl*16 + lr]      = f2bf(d0[reg]);
        sc[16 + lc*4 + reg][ntl*16 + lr] = f2bf(d1[reg]);
      }
    }
    __syncthreads();
    float pm = -1e30f;
    for (int i = 0; i < 64; ++i) pm = fmaxf(pm, b2f(sc[r][cc + 8*i]));
    red[r][cc] = pm;
    __syncthreads();
    float mfull = red[r][0];
    #pragma unroll
    for (int i = 1; i < 8; ++i) mfull = fmaxf(mfull, red[r][i]);
    rowmax[r] = mfull;   // benign same-value race across the 8 threads of a row
    __syncthreads();
    float sum = 0.f;
    for (int i = 0; i < 64; ++i) sum += __expf(b2f(sc[r][cc + 8*i]) - mfull);
    red[r][cc] = sum;
    __syncthreads();
    float ss = 0.f;
    #pragma unroll
    for (int i = 0; i < 8; ++i) ss += red[r][i];
    rowinv[r] = 1.f / ss;
    __syncthreads();
    // PV: each wave one 16x16 tile of the 32x32 O
    const int mt = w4 >> 1, ntd = w4 & 1;
    const int arow = mt*16 + lr;
    const float mrow = rowmax[arow];
    f32x4 o = (f32x4){0.f,0.f,0.f,0.f};
    for (int kt = 0; kt < 16; ++kt){
      bf16x8 sv = *(const bf16x8*)&sc[arow][kt*32 + lc*8];
      bf16x8 ap;
      #pragma unroll
      for (int e = 0; e < 8; ++e){
        float p = __expf(b2f((unsigned short)sv[e]) - mrow);
        ap[e] = (short)f2bf(p);
      }
      bf16x8 bv = *(const bf16x8*)(vb + (size_t)(ntd*16 + lr)*512 + kt*32 + lc*8);
      o = __builtin_amdgcn_mfma_f32_16x16x32_bf16(ap, bv, o, 0, 0, 0);
    }
    #pragma unroll
    for (int reg = 0; reg < 4; ++reg){
      int row = mt*16 + lc*4 + reg;
      int d = ntd*16 + lr;
      float val = o[reg] * rowinv[row];
      ctx[((size_t)(s0 + row)*64 + n)*256 + h*32 + d] = f2bf(val);
    }
    __syncthreads();
  }
}

// K3: attn_out = ctx @ mha_out_w.T + b -> combined[:, 256:512]
__global__ __launch_bounds__(256) void k_outproj(const unsigned short* __restrict__ ctx,
                                                 const float* __restrict__ w,
                                                 const float* __restrict__ bias,
                                                 unsigned short* __restrict__ comb){
  const int nt = blockIdx.x;   // 0..3
  const int mt = blockIdx.y;   // 0..511
  __shared__ unsigned short Bs[64][264];
  const int t = threadIdx.x;
  {
    int row = t >> 2, c0 = (t & 3) * 64;
    const float* src = w + (size_t)(nt*64 + row)*256 + c0;
    #pragma unroll
    for (int i = 0; i < 64; i += 4){
      float4 f = *(const float4*)(src + i);
      *(ushort4*)&Bs[row][c0 + i] = f4tobf(f);
    }
  }
  __syncthreads();
  const int w4 = t >> 6, l = t & 63, lr = l & 15, lc = l >> 4;
  f32x4 acc[4];
  #pragma unroll
  for (int i = 0; i < 4; ++i) acc[i] = (f32x4){0.f,0.f,0.f,0.f};
  const size_t arow = (size_t)(mt*64 + w4*16 + lr) * 256;
  #pragma unroll
  for (int kt = 0; kt < 8; ++kt){
    bf16x8 a = *(const bf16x8*)(ctx + arow + kt*32 + lc*8);
    #pragma unroll
    for (int n4 = 0; n4 < 4; ++n4){
      bf16x8 b = *(const bf16x8*)&Bs[n4*16 + lr][kt*32 + lc*8];
      acc[n4] = __builtin_amdgcn_mfma_f32_16x16x32_bf16(a, b, acc[n4], 0, 0, 0);
    }
  }
  #pragma unroll
  for (int n4 = 0; n4 < 4; ++n4){
    int ncol = nt*64 + n4*16 + lr;
    float bv = bias[ncol];
    #pragma unroll
    for (int reg = 0; reg < 4; ++reg){
      int m = mt*64 + w4*16 + lc*4 + reg;
      comb[(size_t)m*512 + 256 + ncol] = f2bf(acc[n4][reg] + bv);
    }
  }
}

// K4: gates_x = combined @ w_ih.T + (b_ih + b_hh), 128x128 tiles, BK=64.
// Output layout for k_lstm: gates[m][u][gate] = m*2048 + u*4 + gate  (m = st*64 + n).
__global__ __launch_bounds__(256) void k_gates(const unsigned short* __restrict__ A,
                                               const unsigned short* __restrict__ B,
                                               const float* __restrict__ bih,
                                               const float* __restrict__ bhh,
                                               unsigned short* __restrict__ gates){
  const int ntile = blockIdx.x;  // 0..15
  const int mtile = blockIdx.y;  // 0..255
  __shared__ unsigned short As[128][72], Bss[128][72];
  const int t = threadIdx.x, w4 = t >> 6, l = t & 63, lr = l & 15, lc = l >> 4;
  const int wm = w4 >> 1, wn = w4 & 1;
  f32x4 acc[4][4];
  #pragma unroll
  for (int i = 0; i < 4; ++i)
    #pragma unroll
    for (int j = 0; j < 4; ++j) acc[i][j] = (f32x4){0.f,0.f,0.f,0.f};
  const int srow = t >> 1, half = t & 1;
  const unsigned short* sa = A + (size_t)(mtile*128 + srow)*512 + half*32;
  const unsigned short* sb = B + (size_t)(ntile*128 + srow)*512 + half*32;
  for (int kkk = 0; kkk < 8; ++kkk){
    #pragma unroll
    for (int i = 0; i < 4; ++i){
      *(uint4*)&As [srow][half*32 + i*8] = *(const uint4*)(sa + kkk*64 + i*8);
      *(uint4*)&Bss[srow][half*32 + i*8] = *(const uint4*)(sb + kkk*64 + i*8);
    }
    __syncthreads();
    #pragma unroll
    for (int kt = 0; kt < 2; ++kt){
      bf16x8 af[4], bfr[4];
      #pragma unroll
      for (int i = 0; i < 4; ++i) af[i]  = *(const bf16x8*)&As [wm*64 + i*16 + lr][kt*32 + lc*8];
      #pragma unroll
      for (int i = 0; i < 4; ++i) bfr[i] = *(const bf16x8*)&Bss[wn*64 + i*16 + lr][kt*32 + lc*8];
      #pragma unroll
      for (int i = 0; i < 4; ++i)
        #pragma unroll
        for (int j = 0; j < 4; ++j)
          acc[i][j] = __builtin_amdgcn_mfma_f32_16x16x32_bf16(af[i], bfr[j], acc[i][j], 0, 0, 0);
    }
    __syncthreads();
  }
  #pragma unroll
  for (int i = 0; i < 4; ++i){
    #pragma unroll
    for (int j = 0; j < 4; ++j){
      int ncol = ntile*128 + wn*64 + j*16 + lr;
      int gate = ncol >> 9, u = ncol & 511;
      float bsum = bih[ncol] + bhh[ncol];
      #pragma unroll
      for (int reg = 0; reg < 4; ++reg){
        int m = mtile*128 + wm*64 + i*16 + lc*4 + reg;
        gates[(size_t)m*2048 + u*4 + gate] = f2bf(acc[i][j][reg] + bsum);
      }
    }
  }
}

// K5: persistent LSTM, XCD-local. Launch 512 WGs; 88KB LDS -> 1 WG/CU, 32/XCD.
// Claim: g = physical XCC_ID, slot = atomicAdd(cnt[g]); slot>=32 -> exit.
// R12 handshake: role-split waves, wave-level early flags, LDS relay, 1 barrier/step.
__global__ __launch_bounds__(256, 1) void k_lstm(const float* __restrict__ whh,
                                                 const unsigned short* __restrict__ gates,
                                                 unsigned short* __restrict__ ring,
                                                 float* __restrict__ pooled,
                                                 int* __restrict__ flagsIC,
                                                 int* __restrict__ flr,
                                                 int* __restrict__ cnt){
  __shared__ unsigned short Wl[64][512];   // 64KB: rows = gate*16+unit
  __shared__ f32x4 Dg[2][4*2*16];          // 4KB: double-buffered by st&1
  __shared__ float padlds[5120];           // 20KB pad -> 88.6KB total -> 1 WG/CU
  __shared__ int s_hdr[2];
  __shared__ int s_ready;                  // LDS relay: last step confirmed by waves 2-3
  const int t = threadIdx.x, w4 = t >> 6, l = t & 63, lr = l & 15, lc = l >> 4;
  if ((int)blockIdx.x == -1) ((volatile float*)padlds)[0] = 1.f;  // keep padlds
  if (t == 0){
    unsigned xcc;
    asm volatile("s_getreg_b32 %0, hwreg(HW_REG_XCC_ID)" : "=s"(xcc));
    int g = (int)(xcc & 7);
    s_hdr[0] = g;
    s_hdr[1] = atomicAdd(&cnt[g], 1);      // device-scope claim
    s_ready = 0;
  }
  __syncthreads();
  const int g = s_hdr[0], slot = s_hdr[1];
  if (slot >= 32) return;                  // spare WG: free the CU immediately
  const int j0 = slot * 16;
  { // stage w_hh slice fp32->bf16, chunk swizzle phys = logical ^ (row&7)
    const int row = t >> 2;
    const int gate = row >> 4, u = row & 15;
    const float* src = whh + (size_t)(gate*512 + j0 + u) * 512;
    const int cbase = (t & 3) * 16;
    #pragma unroll
    for (int i = 0; i < 16; ++i){
      const int lch = cbase + i;
      float4 f0 = *(const float4*)(src + lch*8);
      float4 f1 = *(const float4*)(src + lch*8 + 4);
      const int pch = lch ^ (row & 7);
      *(ushort4*)&Wl[row][pch*8]     = f4tobf(f0);
      *(ushort4*)&Wl[row][pch*8 + 4] = f4tobf(f1);
    }
  }
  const int eb = t >> 4, eu = t & 15;      // elementwise ownership, t<128: (batch, unit)
  float cst = 0.f, pool = 0.f;
  unsigned long long gx = 0, nx = 0;
  if (t < 128)
    gx = *(const unsigned long long*)(gates + (size_t)(g*8 + eb)*2048 + (j0 + eu)*4);
  __syncthreads();                         // Wl staged; s_ready visible
  for (int st = 0; st < 512; ++st){
    if (st > 0){
      if (t >= 128){
        // waves 2-3: poll global wave-flags for st (overlaps waves 0-1's elementwise
        // tail of st-1). Lane l checks flag l (64 wave-flags = 32 slots x 2 waves).
        bool ok = false;
        #pragma unroll 1
        for (int r = 0; r < 4 && !ok; ++r){
          int v = ((volatile const int*)flr)[(st*4 + r)*512 + g*64 + l];
          ok = (bool)__all(v != 0);
        }
        if (!ok){
          int t2 = 0;   // IC fallback: bounded, correct-by-delay, never hangs
          while (!__all(__hip_atomic_load(&flagsIC[(g*64 + l)*8],
                         __ATOMIC_RELAXED, __HIP_MEMORY_SCOPE_AGENT) >= st)
                 && ++t2 < 20000) { }
        }
        if (l == 0) *(volatile int*)&s_ready = st;   // relay to waves 0-1 (LDS, CU-local)
      } else {
        while (*(volatile int*)&s_ready < st) { }    // ~30cy/iter ds_read spin
      }
    }
    // h(st) @ Wl^T : A rows = 8 batches (lr&7, duplicated), wave w4 = gate w4.
    // areg L2 burst (flag-gated -> guaranteed valid), nx HBM prefetch LAST.
    const unsigned short* ha = ring + (((size_t)st*8 + g) << 12) + (lr & 7)*512 + lc*8;
    bf16x8 areg[16];
    #pragma unroll
    for (int kt = 0; kt < 16; ++kt) areg[kt] = *(const bf16x8*)(ha + kt*32);
    if (st < 511 && t < 128)
      nx = *(const unsigned long long*)(gates + ((size_t)(st+1)*64 + g*8 + eb)*2048 + (j0 + eu)*4);
    f32x4 ac0 = (f32x4){0.f,0.f,0.f,0.f}, ac1 = (f32x4){0.f,0.f,0.f,0.f};
    f32x4 ac2 = (f32x4){0.f,0.f,0.f,0.f}, ac3 = (f32x4){0.f,0.f,0.f,0.f};
    #pragma unroll
    for (int kt = 0; kt < 16; kt += 4){
      bf16x8 b0 = *(const bf16x8*)&Wl[w4*16 + lr][(((kt  )*4 + lc) ^ (lr & 7)) * 8];
      bf16x8 b1 = *(const bf16x8*)&Wl[w4*16 + lr][(((kt+1)*4 + lc) ^ (lr & 7)) * 8];
      bf16x8 b2 = *(const bf16x8*)&Wl[w4*16 + lr][(((kt+2)*4 + lc) ^ (lr & 7)) * 8];
      bf16x8 b3 = *(const bf16x8*)&Wl[w4*16 + lr][(((kt+3)*4 + lc) ^ (lr & 7)) * 8];
      ac0 = __builtin_amdgcn_mfma_f32_16x16x32_bf16(areg[kt  ], b0, ac0, 0, 0, 0);
      ac1 = __builtin_amdgcn_mfma_f32_16x16x32_bf16(areg[kt+1], b1, ac1, 0, 0, 0);
      ac2 = __builtin_amdgcn_mfma_f32_16x16x32_bf16(areg[kt+2], b2, ac2, 0, 0, 0);
      ac3 = __builtin_amdgcn_mfma_f32_16x16x32_bf16(areg[kt+3], b3, ac3, 0, 0, 0);
    }
    f32x4 acc = (ac0 + ac1) + (ac2 + ac3);
    const int p = st & 1;
    if (lc < 2) Dg[p][(w4*2 + lc)*16 + lr] = acc;   // D: col=unit(lane&15), row=batch(lc*4+reg)
    __syncthreads();   // THE one barrier per step
    if (t < 128){
      union { unsigned long long q; unsigned short u[4]; } ga; ga.q = gx;
      const int dq = (eb >> 2)*16 + eu, dr = eb & 3;
      float gi = Dg[p][0*32 + dq][dr] + b2f(ga.u[0]);
      float gf = Dg[p][1*32 + dq][dr] + b2f(ga.u[1]);
      float gc = Dg[p][2*32 + dq][dr] + b2f(ga.u[2]);
      float go = Dg[p][3*32 + dq][dr] + b2f(ga.u[3]);
      float i_ = __builtin_amdgcn_rcpf(1.f + __expf(-gi));
      float f_ = __builtin_amdgcn_rcpf(1.f + __expf(-gf));
      float cg = fminf(fmaxf(gc, -20.f), 20.f);
      float e2 = __expf(2.f * cg);
      float g_ = 1.f - 2.f * __builtin_amdgcn_rcpf(e2 + 1.f);
      float o_ = __builtin_amdgcn_rcpf(1.f + __expf(-go));
      float cn = f_ * cst + i_ * g_;
      cst = cn;
      float ct = fminf(fmaxf(cn, -20.f), 20.f);
      float e2c = __expf(2.f * ct);
      float th = 1.f - 2.f * __builtin_amdgcn_rcpf(e2c + 1.f);
      float hh = o_ * th;
      pool += hh;
      if (st < 511){
        // plain write-through h store -> this XCD's L2
        ring[(((size_t)(st+1)*8 + g) << 12) + eb*512 + j0 + eu] = f2bf(hh);
        // per-wave drain: THIS wave's h stores acked in L2 before its flags go out.
        asm volatile("s_waitcnt vmcnt(0)" ::: "memory");
        // wave-level flags: 4 fresh-address L2 replicas + 1 IC fallback.
        if (l < 4) flr[((st+1)*4 + l)*512 + g*64 + slot*2 + w4] = 1;
        if (l == 0)
          __hip_atomic_store(&flagsIC[(g*64 + slot*2 + w4)*8], st + 1,
                             __ATOMIC_RELAXED, __HIP_MEMORY_SCOPE_AGENT);
      }
      gx = nx;
    }
  }
  if (t < 128)
    pooled[(size_t)(g*8 + eb)*512 + j0 + eu] = pool * (1.f / 512.f);
}

// K6: out = log_sigmoid(pooled @ proj_w.T + proj_b)
__global__ __launch_bounds__(256) void k_final(const float* __restrict__ pooled,
                                               const float* __restrict__ w,
                                               const float* __restrict__ bias,
                                               float* __restrict__ out){
  const int n = blockIdx.x;
  __shared__ float pr[512];
  const int t = threadIdx.x;
  pr[t]       = pooled[(size_t)n*512 + t];
  pr[t + 256] = pooled[(size_t)n*512 + t + 256];
  __syncthreads();
  const float* wr = w + (size_t)t * 512;
  float s = bias[t];
  for (int i = 0; i < 512; i += 4){
    float4 f = *(const float4*)(wr + i);
    s += f.x*pr[i] + f.y*pr[i+1] + f.z*pr[i+2] + f.w*pr[i+3];
  }
  float rres = fminf(s, 0.f) - log1pf(__expf(-fabsf(s)));
  out[(size_t)n*256 + t] = rres;
}

extern "C" void kernel_launch(void* const* d_in, const int* in_sizes, int n_in,
                              void* d_out, int out_size, void* d_ws, size_t ws_size,
                              hipStream_t stream){
  const float* x      = (const float*)d_in[0];
  const float* in_w   = (const float*)d_in[1];
  const float* in_b   = (const float*)d_in[2];
  const float* mo_w   = (const float*)d_in[3];
  const float* mo_b   = (const float*)d_in[4];
  const float* w_ih   = (const float*)d_in[5];
  const float* w_hh   = (const float*)d_in[6];
  const float* b_ih   = (const float*)d_in[7];
  const float* b_hh   = (const float*)d_in[8];
  const float* proj_w = (const float*)d_in[9];
  const float* proj_b = (const float*)d_in[10];
  uint8_t* ws = (uint8_t*)d_ws;
  int*            flagsIC = (int*)(ws + 0x0);
  int*            cnt     = (int*)(ws + 0x4000);
  float*          pooled  = (float*)(ws + 0x30000);
  unsigned short* wihbf   = (unsigned short*)(ws + 0x50000);
  int*            flr     = (int*)(ws + 0x300000);
  unsigned short* comb    = (unsigned short*)(ws + 0x800000);  // doubles as h-ring in k_lstm
  unsigned short* gates   = (unsigned short*)(ws + 0x3000000);
  unsigned short* qbuf    = (unsigned short*)(ws + 0x3000000); // aliases gates (dead before k_gates)
  unsigned short* kbuf    = (unsigned short*)(ws + 0x4000000);
  unsigned short* vbuf    = (unsigned short*)(ws + 0x5000000);
  unsigned short* ctx     = (unsigned short*)(ws + 0x6000000);

  hipMemsetAsync(ws + 0x300000, 0, 0x400000, stream);  // flr
  hipMemsetAsync(ws, 0, 0x4020, stream);               // flagsIC + cnt
  hipLaunchKernelGGL(k_convert, dim3(9216),    dim3(256), 0, stream, w_ih, x, wihbf, comb);
  hipLaunchKernelGGL(k_qkv,     dim3(12, 512), dim3(256), 0, stream, comb, in_w, in_b, qbuf, kbuf, vbuf);
  hipLaunchKernelGGL(k_attn,    dim3(512),     dim3(256), 0, stream, qbuf, kbuf, vbuf, ctx);
  hipLaunchKernelGGL(k_outproj, dim3(4, 512),  dim3(256), 0, stream, ctx, mo_w, mo_b, comb);
  hipLaunchKernelGGL(k_gates,   dim3(16, 256), dim3(256), 0, stream, comb, wihbf, b_ih, b_hh, gates);
  hipMemsetAsync(comb, 0, 0x10000, stream);  // h-ring slot 0 = h(-1) = zeros (comb dead now)
  hipLaunchKernelGGL(k_lstm,    dim3(512),     dim3(256), 0, stream, w_hh, gates, comb, pooled, flagsIC, flr, cnt);
  hipLaunchKernelGGL(k_final,   dim3(64),      dim3(256), 0, stream, pooled, proj_w, proj_b, (float*)d_out);
}

// Round 7
// 2138.655 us; speedup vs baseline: 1.8363x; 1.0096x over previous
//
#include <hip/hip_runtime.h>
#include <hip/hip_bf16.h>
#include <stdint.h>

// Problem: S=512, N=64, E=256, NH=8, HD=32, LH=512.
// Pipeline: convert -> qkv -> attn -> outproj -> gates GEMM -> persistent LSTM -> final proj.
// R13: wave-autonomous k_lstm — ZERO intra-WG barriers in the 512-step loop.
//  - Ownership: wave w of slot owns units [j0+w*4, j0+w*4+4) x 4 gates x 8 batches,
//    end-to-end. Wl rows reordered: row = w*16 + q*4 + gate  <->  whh row gate*512+j0+(row>>2),
//    so the wave's MFMA D-tile (col = q*4+gate) holds ALL 4 gates of its own units.
//  - Gate gather = wave-private LDS transpose (ds_write, lgkmcnt(0), ds_read_b128):
//    same-wave producer/consumer -> no barrier. Elementwise in-wave (lanes 0-31,
//    one (batch,unit) each). Dg buffer + its barrier deleted.
//  - Per-wave publish: h stores -> per-wave s_waitcnt vmcnt(0) -> 8 byte-replica flags
//    (4 waves packed per u32 word per slot -> consumer polls ONE u32 per slot) + IC
//    fallback flag. Flag-implies-h: same-L2 ordering as R5..R10.
//  - Poll: every wave gates independently on all 32 slot-words (fresh-address replica
//    walk r=0..7, R10-proven primitive; IC __hip_atomic fallback, bounded). Max drift
//    between waves = 1 step (self-limited by the gate). R12's failure (poll too early,
//    replicas exhausted -> IC every step) does not apply: each wave polls right before
//    it needs the data, after its own full step's work.
// Kept: areg burst + 4 MFMA chains, nx prefetch post-gate, v_rcp elementwise.

typedef __attribute__((ext_vector_type(8))) short bf16x8;
typedef __attribute__((ext_vector_type(4))) float f32x4;

__device__ __forceinline__ unsigned short f2bf(float f){
  unsigned u = __float_as_uint(f);
  u += 0x7FFFu + ((u >> 16) & 1u);          // RNE
  return (unsigned short)(u >> 16);
}
__device__ __forceinline__ float b2f(unsigned short h){
  return __uint_as_float(((unsigned)h) << 16);
}
__device__ __forceinline__ ushort4 f4tobf(float4 f){
  ushort4 o; o.x=f2bf(f.x); o.y=f2bf(f.y); o.z=f2bf(f.z); o.w=f2bf(f.w); return o;
}

// ---------------- workspace layout (bytes) ----------------
// flagsIC:  [0x0,      0x1000)   8 groups x 128 wave-flags, 4B stride (IC fallback)
// cnt:      [0x4000,   0x4020)   8 ints, per-XCD slot claim
// pooled:   [0x30000,  0x50000)  64x512 f32
// w_ih bf16:[0x50000,  0x250000)
// flr:      [0x300000, 0x700000) byte-packed wave flags: [st][r<8][g][32 slot-words u32,
//           byte w4 of word slot] = 4MB exactly
// combined: [0x800000, 0x2800000) 32768x512 bf16; REUSED by k_lstm as h-ring:
//           ring[st][g] = 8KB (8 batches x 512 units bf16), 64KB/step, 32MB total
// gates:    [0x3000000,0xB000000) layout [m][u][gate] = m*2048 + u*4 + gate (aliases q/k/v/ctx)
// q:0x3000000 k:0x4000000 v:0x5000000 ctx:0x6000000 (each 16MB bf16)
// total required ws: 0xB000000 = 184,549,376 B

// K0: w_ih fp32->bf16, and x fp32 -> combined[:, 0:256] bf16
__global__ __launch_bounds__(256) void k_convert(const float* __restrict__ wih,
                                                 const float* __restrict__ x,
                                                 unsigned short* __restrict__ wih_bf,
                                                 unsigned short* __restrict__ comb){
  size_t i = ((size_t)blockIdx.x * 256 + threadIdx.x) * 4;
  if (i < 1048576){
    float4 f = *(const float4*)(wih + i);
    *(ushort4*)(wih_bf + i) = f4tobf(f);
  } else {
    size_t j = i - 1048576;
    if (j < 8388608){
      float4 f = *(const float4*)(x + j);
      size_t m = j >> 8, c = j & 255;
      *(ushort4*)(comb + m*512 + c) = f4tobf(f);
    }
  }
}

// K1: qkv = x @ in_proj_w.T + b ; scale folded into q; writes q/k [n][h][s][d], v transposed [n][h][d][s]
__global__ __launch_bounds__(256) void k_qkv(const unsigned short* __restrict__ xb,
                                             const float* __restrict__ w,
                                             const float* __restrict__ bias,
                                             unsigned short* __restrict__ q,
                                             unsigned short* __restrict__ kk,
                                             unsigned short* __restrict__ v){
  const int nt = blockIdx.x;    // 0..11
  const int mt = blockIdx.y;    // 0..511  (= s, since M-row = s*64+n)
  __shared__ unsigned short Bs[64][264];
  const int t = threadIdx.x;
  { // stage+convert B tile (in_proj_w rows nt*64..+64, k 0..256)
    int row = t >> 2, c0 = (t & 3) * 64;
    const float* src = w + (size_t)(nt*64 + row)*256 + c0;
    #pragma unroll
    for (int i = 0; i < 64; i += 4){
      float4 f = *(const float4*)(src + i);
      *(ushort4*)&Bs[row][c0 + i] = f4tobf(f);
    }
  }
  __syncthreads();
  const int w4 = t >> 6, l = t & 63, lr = l & 15, lc = l >> 4;
  f32x4 acc[4];
  #pragma unroll
  for (int i = 0; i < 4; ++i) acc[i] = (f32x4){0.f,0.f,0.f,0.f};
  const size_t arow = (size_t)(mt*64 + w4*16 + lr) * 512;  // A from combined (bf16 x)
  #pragma unroll
  for (int kt = 0; kt < 8; ++kt){
    bf16x8 a = *(const bf16x8*)(xb + arow + kt*32 + lc*8);
    #pragma unroll
    for (int n4 = 0; n4 < 4; ++n4){
      bf16x8 b = *(const bf16x8*)&Bs[n4*16 + lr][kt*32 + lc*8];
      acc[n4] = __builtin_amdgcn_mfma_f32_16x16x32_bf16(a, b, acc[n4], 0, 0, 0);
    }
  }
  const int s = mt;
  #pragma unroll
  for (int n4 = 0; n4 < 4; ++n4){
    int ncol = nt*64 + n4*16 + lr;
    float bv = bias[ncol];
    int which = ncol >> 8, rem = ncol & 255, hh = rem >> 5, d = rem & 31;
    #pragma unroll
    for (int reg = 0; reg < 4; ++reg){
      int nb = w4*16 + lc*4 + reg;   // batch
      float val = acc[n4][reg] + bv;
      if (which == 0){
        val *= 0.17677669529663687f;  // 1/sqrt(32)
        q[((size_t)(nb*8 + hh)*512 + s)*32 + d] = f2bf(val);
      } else if (which == 1){
        kk[((size_t)(nb*8 + hh)*512 + s)*32 + d] = f2bf(val);
      } else {
        v[((size_t)(nb*8 + hh)*32 + d)*512 + s] = f2bf(val);
      }
    }
  }
}

// K2: attention for one (n,h); Q-tile=32, full-S bf16 score strip in LDS, exp recomputed into PV A-frags
__global__ __launch_bounds__(256) void k_attn(const unsigned short* __restrict__ q,
                                              const unsigned short* __restrict__ k,
                                              const unsigned short* __restrict__ v,
                                              unsigned short* __restrict__ ctx){
  const int nh = blockIdx.x;
  const int n = nh >> 3, h = nh & 7;
  __shared__ unsigned short sc[32][520];
  __shared__ float red[32][8];
  __shared__ float rowmax[32], rowinv[32];
  const unsigned short* qb = q + (size_t)nh * 512 * 32;
  const unsigned short* kb = k + (size_t)nh * 512 * 32;
  const unsigned short* vb = v + (size_t)nh * 32 * 512;
  const int t = threadIdx.x, w4 = t >> 6, l = t & 63, lr = l & 15, lc = l >> 4;
  const int r = t >> 3, cc = t & 7;
  for (int qt = 0; qt < 16; ++qt){
    const int s0 = qt * 32;
    bf16x8 aq0 = *(const bf16x8*)(qb + (size_t)(s0 + lr)*32 + lc*8);
    bf16x8 aq1 = *(const bf16x8*)(qb + (size_t)(s0 + 16 + lr)*32 + lc*8);
    #pragma unroll
    for (int j = 0; j < 8; ++j){
      int ntl = w4*8 + j;
      bf16x8 bk = *(const bf16x8*)(kb + (size_t)(ntl*16 + lr)*32 + lc*8);
      f32x4 d0 = (f32x4){0.f,0.f,0.f,0.f}, d1 = (f32x4){0.f,0.f,0.f,0.f};
      d0 = __builtin_amdgcn_mfma_f32_16x16x32_bf16(aq0, bk, d0, 0, 0, 0);
      d1 = __builtin_amdgcn_mfma_f32_16x16x32_bf16(aq1, bk, d1, 0, 0, 0);
      #pragma unroll
      for (int reg = 0; reg < 4; ++reg){
        sc[lc*4 + reg][ntl*16 + lr]      = f2bf(d0[reg]);
        sc[16 + lc*4 + reg][ntl*16 + lr] = f2bf(d1[reg]);
      }
    }
    __syncthreads();
    float pm = -1e30f;
    for (int i = 0; i < 64; ++i) pm = fmaxf(pm, b2f(sc[r][cc + 8*i]));
    red[r][cc] = pm;
    __syncthreads();
    float mfull = red[r][0];
    #pragma unroll
    for (int i = 1; i < 8; ++i) mfull = fmaxf(mfull, red[r][i]);
    rowmax[r] = mfull;   // benign same-value race across the 8 threads of a row
    __syncthreads();
    float sum = 0.f;
    for (int i = 0; i < 64; ++i) sum += __expf(b2f(sc[r][cc + 8*i]) - mfull);
    red[r][cc] = sum;
    __syncthreads();
    float ss = 0.f;
    #pragma unroll
    for (int i = 0; i < 8; ++i) ss += red[r][i];
    rowinv[r] = 1.f / ss;
    __syncthreads();
    // PV: each wave one 16x16 tile of the 32x32 O
    const int mt = w4 >> 1, ntd = w4 & 1;
    const int arow = mt*16 + lr;
    const float mrow = rowmax[arow];
    f32x4 o = (f32x4){0.f,0.f,0.f,0.f};
    for (int kt = 0; kt < 16; ++kt){
      bf16x8 sv = *(const bf16x8*)&sc[arow][kt*32 + lc*8];
      bf16x8 ap;
      #pragma unroll
      for (int e = 0; e < 8; ++e){
        float p = __expf(b2f((unsigned short)sv[e]) - mrow);
        ap[e] = (short)f2bf(p);
      }
      bf16x8 bv = *(const bf16x8*)(vb + (size_t)(ntd*16 + lr)*512 + kt*32 + lc*8);
      o = __builtin_amdgcn_mfma_f32_16x16x32_bf16(ap, bv, o, 0, 0, 0);
    }
    #pragma unroll
    for (int reg = 0; reg < 4; ++reg){
      int row = mt*16 + lc*4 + reg;
      int d = ntd*16 + lr;
      float val = o[reg] * rowinv[row];
      ctx[((size_t)(s0 + row)*64 + n)*256 + h*32 + d] = f2bf(val);
    }
    __syncthreads();
  }
}

// K3: attn_out = ctx @ mha_out_w.T + b -> combined[:, 256:512]
__global__ __launch_bounds__(256) void k_outproj(const unsigned short* __restrict__ ctx,
                                                 const float* __restrict__ w,
                                                 const float* __restrict__ bias,
                                                 unsigned short* __restrict__ comb){
  const int nt = blockIdx.x;   // 0..3
  const int mt = blockIdx.y;   // 0..511
  __shared__ unsigned short Bs[64][264];
  const int t = threadIdx.x;
  {
    int row = t >> 2, c0 = (t & 3) * 64;
    const float* src = w + (size_t)(nt*64 + row)*256 + c0;
    #pragma unroll
    for (int i = 0; i < 64; i += 4){
      float4 f = *(const float4*)(src + i);
      *(ushort4*)&Bs[row][c0 + i] = f4tobf(f);
    }
  }
  __syncthreads();
  const int w4 = t >> 6, l = t & 63, lr = l & 15, lc = l >> 4;
  f32x4 acc[4];
  #pragma unroll
  for (int i = 0; i < 4; ++i) acc[i] = (f32x4){0.f,0.f,0.f,0.f};
  const size_t arow = (size_t)(mt*64 + w4*16 + lr) * 256;
  #pragma unroll
  for (int kt = 0; kt < 8; ++kt){
    bf16x8 a = *(const bf16x8*)(ctx + arow + kt*32 + lc*8);
    #pragma unroll
    for (int n4 = 0; n4 < 4; ++n4){
      bf16x8 b = *(const bf16x8*)&Bs[n4*16 + lr][kt*32 + lc*8];
      acc[n4] = __builtin_amdgcn_mfma_f32_16x16x32_bf16(a, b, acc[n4], 0, 0, 0);
    }
  }
  #pragma unroll
  for (int n4 = 0; n4 < 4; ++n4){
    int ncol = nt*64 + n4*16 + lr;
    float bv = bias[ncol];
    #pragma unroll
    for (int reg = 0; reg < 4; ++reg){
      int m = mt*64 + w4*16 + lc*4 + reg;
      comb[(size_t)m*512 + 256 + ncol] = f2bf(acc[n4][reg] + bv);
    }
  }
}

// K4: gates_x = combined @ w_ih.T + (b_ih + b_hh), 128x128 tiles, BK=64.
// Output layout for k_lstm: gates[m][u][gate] = m*2048 + u*4 + gate  (m = st*64 + n).
__global__ __launch_bounds__(256) void k_gates(const unsigned short* __restrict__ A,
                                               const unsigned short* __restrict__ B,
                                               const float* __restrict__ bih,
                                               const float* __restrict__ bhh,
                                               unsigned short* __restrict__ gates){
  const int ntile = blockIdx.x;  // 0..15
  const int mtile = blockIdx.y;  // 0..255
  __shared__ unsigned short As[128][72], Bss[128][72];
  const int t = threadIdx.x, w4 = t >> 6, l = t & 63, lr = l & 15, lc = l >> 4;
  const int wm = w4 >> 1, wn = w4 & 1;
  f32x4 acc[4][4];
  #pragma unroll
  for (int i = 0; i < 4; ++i)
    #pragma unroll
    for (int j = 0; j < 4; ++j) acc[i][j] = (f32x4){0.f,0.f,0.f,0.f};
  const int srow = t >> 1, half = t & 1;
  const unsigned short* sa = A + (size_t)(mtile*128 + srow)*512 + half*32;
  const unsigned short* sb = B + (size_t)(ntile*128 + srow)*512 + half*32;
  for (int kkk = 0; kkk < 8; ++kkk){
    #pragma unroll
    for (int i = 0; i < 4; ++i){
      *(uint4*)&As [srow][half*32 + i*8] = *(const uint4*)(sa + kkk*64 + i*8);
      *(uint4*)&Bss[srow][half*32 + i*8] = *(const uint4*)(sb + kkk*64 + i*8);
    }
    __syncthreads();
    #pragma unroll
    for (int kt = 0; kt < 2; ++kt){
      bf16x8 af[4], bfr[4];
      #pragma unroll
      for (int i = 0; i < 4; ++i) af[i]  = *(const bf16x8*)&As [wm*64 + i*16 + lr][kt*32 + lc*8];
      #pragma unroll
      for (int i = 0; i < 4; ++i) bfr[i] = *(const bf16x8*)&Bss[wn*64 + i*16 + lr][kt*32 + lc*8];
      #pragma unroll
      for (int i = 0; i < 4; ++i)
        #pragma unroll
        for (int j = 0; j < 4; ++j)
          acc[i][j] = __builtin_amdgcn_mfma_f32_16x16x32_bf16(af[i], bfr[j], acc[i][j], 0, 0, 0);
    }
    __syncthreads();
  }
  #pragma unroll
  for (int i = 0; i < 4; ++i){
    #pragma unroll
    for (int j = 0; j < 4; ++j){
      int ncol = ntile*128 + wn*64 + j*16 + lr;
      int gate = ncol >> 9, u = ncol & 511;
      float bsum = bih[ncol] + bhh[ncol];
      #pragma unroll
      for (int reg = 0; reg < 4; ++reg){
        int m = mtile*128 + wm*64 + i*16 + lc*4 + reg;
        gates[(size_t)m*2048 + u*4 + gate] = f2bf(acc[i][j][reg] + bsum);
      }
    }
  }
}

// K5: persistent LSTM, XCD-local, wave-autonomous. Launch 512 WGs; 86KB LDS -> 1 WG/CU.
// Claim: g = physical XCC_ID, slot = atomicAdd(cnt[g]); slot>=32 -> exit.
// No __syncthreads in the 512-step loop. Wave w owns units [j0+w*4, j0+w*4+4).
__global__ __launch_bounds__(256, 1) void k_lstm(const float* __restrict__ whh,
                                                 const unsigned short* __restrict__ gates,
                                                 unsigned short* __restrict__ ring,
                                                 float* __restrict__ pooled,
                                                 int* __restrict__ flagsIC,
                                                 unsigned* __restrict__ flr,
                                                 int* __restrict__ cnt){
  __shared__ unsigned short Wl[64][512];   // 64KB: row = w*16 + q*4 + gate
  __shared__ float scr[4][128];            // 2KB: wave-private transpose scratch
  __shared__ float padlds[5120];           // 20KB pad -> ~86KB total -> 1 WG/CU
  __shared__ int s_hdr[2];
  const int t = threadIdx.x, w4 = t >> 6, l = t & 63, lr = l & 15, lc = l >> 4;
  if ((int)blockIdx.x == -1) ((volatile float*)padlds)[0] = 1.f;  // keep padlds
  if (t == 0){
    unsigned xcc;
    asm volatile("s_getreg_b32 %0, hwreg(HW_REG_XCC_ID)" : "=s"(xcc));
    s_hdr[0] = (int)(xcc & 7);
    s_hdr[1] = atomicAdd(&cnt[xcc & 7], 1);   // device-scope claim
  }
  __syncthreads();
  const int g = s_hdr[0], slot = s_hdr[1];
  if (slot >= 32) return;                  // spare WG: free the CU immediately
  const int j0 = slot * 16;
  { // stage w_hh slice fp32->bf16. Wl row r = w*16+q*4+gate <-> whh row (r&3)*512 + j0 + (r>>2).
    // chunk swizzle phys = logical ^ (row&7), matching the (lr&7) XOR on the read side.
    const int row = t >> 2;
    const float* src = whh + (size_t)((row & 3)*512 + j0 + (row >> 2)) * 512;
    const int cbase = (t & 3) * 16;
    #pragma unroll
    for (int i = 0; i < 16; ++i){
      const int lch = cbase + i;
      float4 f0 = *(const float4*)(src + lch*8);
      float4 f1 = *(const float4*)(src + lch*8 + 4);
      const int pch = lch ^ (row & 7);
      *(ushort4*)&Wl[row][pch*8]     = f4tobf(f0);
      *(ushort4*)&Wl[row][pch*8 + 4] = f4tobf(f1);
    }
  }
  // lane<32 elementwise ownership: batch b = l>>2 (0..7), unit-quad q = l&3 (0..3)
  const int b = l >> 2, q = l & 3;
  const int ucol = j0 + w4*4 + q;          // absolute unit column
  const int wid = slot*4 + w4;             // wave id within XCD (0..127)
  float cst = 0.f, pool = 0.f;
  unsigned long long gx = 0, nx = 0;
  if (l < 32)
    gx = *(const unsigned long long*)(gates + (size_t)(g*8 + b)*2048 + ucol*4);
  __syncthreads();                         // Wl staged; last barrier before the loop
  for (int st = 0; st < 512; ++st){
    if (st > 0){
      // per-wave gate on h(st): 32 slot-words (4 wave-bytes each), 8 fresh replicas
      bool ok = false;
      #pragma unroll 1
      for (int r = 0; r < 8 && !ok; ++r){
        unsigned wv = 0x01010101u;
        if (l < 32) wv = ((volatile const unsigned*)flr)[((st*8 + r)*8 + g)*32 + l];
        ok = (bool)__all(wv == 0x01010101u);
      }
      if (!ok){
        int t2 = 0;   // IC fallback: bounded, correct-by-delay, never hangs
        for (;;){
          int v0 = __hip_atomic_load(&flagsIC[g*128 + l],      __ATOMIC_RELAXED, __HIP_MEMORY_SCOPE_AGENT);
          int v1 = __hip_atomic_load(&flagsIC[g*128 + 64 + l], __ATOMIC_RELAXED, __HIP_MEMORY_SCOPE_AGENT);
          if (__all((v0 >= st) && (v1 >= st)) || ++t2 >= 20000) break;
        }
      }
    }
    __builtin_amdgcn_sched_barrier(0);
    asm volatile("" ::: "memory");         // forbid hoisting h reads above the gate
    // h(st) @ Wl^T : A rows = 8 batches (lr&7, dup), 16 b128 L2 loads, then nx LAST
    const unsigned short* ha = ring + (((size_t)st*8 + g) << 12) + (lr & 7)*512 + lc*8;
    bf16x8 areg[16];
    #pragma unroll
    for (int kt = 0; kt < 16; ++kt) areg[kt] = *(const bf16x8*)(ha + kt*32);
    if (st < 511 && l < 32)
      nx = *(const unsigned long long*)(gates + ((size_t)(st+1)*64 + g*8 + b)*2048 + ucol*4);
    f32x4 ac0 = (f32x4){0.f,0.f,0.f,0.f}, ac1 = (f32x4){0.f,0.f,0.f,0.f};
    f32x4 ac2 = (f32x4){0.f,0.f,0.f,0.f}, ac3 = (f32x4){0.f,0.f,0.f,0.f};
    #pragma unroll
    for (int kt = 0; kt < 16; kt += 4){
      bf16x8 b0 = *(const bf16x8*)&Wl[w4*16 + lr][(((kt  )*4 + lc) ^ (lr & 7)) * 8];
      bf16x8 b1 = *(const bf16x8*)&Wl[w4*16 + lr][(((kt+1)*4 + lc) ^ (lr & 7)) * 8];
      bf16x8 b2 = *(const bf16x8*)&Wl[w4*16 + lr][(((kt+2)*4 + lc) ^ (lr & 7)) * 8];
      bf16x8 b3 = *(const bf16x8*)&Wl[w4*16 + lr][(((kt+3)*4 + lc) ^ (lr & 7)) * 8];
      ac0 = __builtin_amdgcn_mfma_f32_16x16x32_bf16(areg[kt  ], b0, ac0, 0, 0, 0);
      ac1 = __builtin_amdgcn_mfma_f32_16x16x32_bf16(areg[kt+1], b1, ac1, 0, 0, 0);
      ac2 = __builtin_amdgcn_mfma_f32_16x16x32_bf16(areg[kt+2], b2, ac2, 0, 0, 0);
      ac3 = __builtin_amdgcn_mfma_f32_16x16x32_bf16(areg[kt+3], b3, ac3, 0, 0, 0);
    }
    f32x4 acc = (ac0 + ac1) + (ac2 + ac3);
    // wave-private LDS transpose: D[row=batch(dup), col=q*4+gate] -> scr[b*16+q*4+gate].
    // Same-wave producer/consumer: lgkmcnt(0) + sched fence, NO barrier.
    if (lc < 2){
      #pragma unroll
      for (int r2 = 0; r2 < 4; ++r2)
        scr[w4][(lc*4 + r2)*16 + lr] = acc[r2];
    }
    asm volatile("s_waitcnt lgkmcnt(0)" ::: "memory");
    __builtin_amdgcn_sched_barrier(0);
    if (l < 32){
      f32x4 gq4 = *(const f32x4*)&scr[w4][b*16 + q*4];   // gates i,f,g,o for (b, ucol)
      union { unsigned long long qq; unsigned short u[4]; } ga; ga.qq = gx;
      float gi = gq4[0] + b2f(ga.u[0]);
      float gf = gq4[1] + b2f(ga.u[1]);
      float gc = gq4[2] + b2f(ga.u[2]);
      float go = gq4[3] + b2f(ga.u[3]);
      float i_ = __builtin_amdgcn_rcpf(1.f + __expf(-gi));
      float f_ = __builtin_amdgcn_rcpf(1.f + __expf(-gf));
      float cg = fminf(fmaxf(gc, -20.f), 20.f);
      float e2 = __expf(2.f * cg);
      float g_ = 1.f - 2.f * __builtin_amdgcn_rcpf(e2 + 1.f);
      float o_ = __builtin_amdgcn_rcpf(1.f + __expf(-go));
      float cn = f_ * cst + i_ * g_;
      cst = cn;
      float ct = fminf(fmaxf(cn, -20.f), 20.f);
      float e2c = __expf(2.f * ct);
      float th = 1.f - 2.f * __builtin_amdgcn_rcpf(e2c + 1.f);
      float hh = o_ * th;
      pool += hh;
      if (st < 511)  // plain write-through store -> this XCD's L2
        ring[(((size_t)(st+1)*8 + g) << 12) + b*512 + ucol] = f2bf(hh);
      gx = nx;
    }
    if (st < 511){
      // per-wave drain: THIS wave's h stores acked in L2 before its flags go out
      asm volatile("s_waitcnt vmcnt(0)" ::: "memory");
      if (l < 8)   // 8 byte-replicas: byte w4 of word slot, replica l
        ((unsigned char*)flr)[(size_t)((((st+1)*8 + l)*8 + g)*32 + slot)*4 + w4] = 1;
      if (l == 0)
        __hip_atomic_store(&flagsIC[g*128 + wid], st + 1,
                           __ATOMIC_RELAXED, __HIP_MEMORY_SCOPE_AGENT);
    }
  }
  if (l < 32)
    pooled[(size_t)(g*8 + b)*512 + ucol] = pool * (1.f / 512.f);
}

// K6: out = log_sigmoid(pooled @ proj_w.T + proj_b)
__global__ __launch_bounds__(256) void k_final(const float* __restrict__ pooled,
                                               const float* __restrict__ w,
                                               const float* __restrict__ bias,
                                               float* __restrict__ out){
  const int n = blockIdx.x;
  __shared__ float pr[512];
  const int t = threadIdx.x;
  pr[t]       = pooled[(size_t)n*512 + t];
  pr[t + 256] = pooled[(size_t)n*512 + t + 256];
  __syncthreads();
  const float* wr = w + (size_t)t * 512;
  float s = bias[t];
  for (int i = 0; i < 512; i += 4){
    float4 f = *(const float4*)(wr + i);
    s += f.x*pr[i] + f.y*pr[i+1] + f.z*pr[i+2] + f.w*pr[i+3];
  }
  float rres = fminf(s, 0.f) - log1pf(__expf(-fabsf(s)));
  out[(size_t)n*256 + t] = rres;
}

extern "C" void kernel_launch(void* const* d_in, const int* in_sizes, int n_in,
                              void* d_out, int out_size, void* d_ws, size_t ws_size,
                              hipStream_t stream){
  const float* x      = (const float*)d_in[0];
  const float* in_w   = (const float*)d_in[1];
  const float* in_b   = (const float*)d_in[2];
  const float* mo_w   = (const float*)d_in[3];
  const float* mo_b   = (const float*)d_in[4];
  const float* w_ih   = (const float*)d_in[5];
  const float* w_hh   = (const float*)d_in[6];
  const float* b_ih   = (const float*)d_in[7];
  const float* b_hh   = (const float*)d_in[8];
  const float* proj_w = (const float*)d_in[9];
  const float* proj_b = (const float*)d_in[10];
  uint8_t* ws = (uint8_t*)d_ws;
  int*            flagsIC = (int*)(ws + 0x0);
  int*            cnt     = (int*)(ws + 0x4000);
  float*          pooled  = (float*)(ws + 0x30000);
  unsigned short* wihbf   = (unsigned short*)(ws + 0x50000);
  unsigned*       flr     = (unsigned*)(ws + 0x300000);
  unsigned short* comb    = (unsigned short*)(ws + 0x800000);  // doubles as h-ring in k_lstm
  unsigned short* gates   = (unsigned short*)(ws + 0x3000000);
  unsigned short* qbuf    = (unsigned short*)(ws + 0x3000000); // aliases gates (dead before k_gates)
  unsigned short* kbuf    = (unsigned short*)(ws + 0x4000000);
  unsigned short* vbuf    = (unsigned short*)(ws + 0x5000000);
  unsigned short* ctx     = (unsigned short*)(ws + 0x6000000);

  hipMemsetAsync(ws + 0x300000, 0, 0x400000, stream);  // flr
  hipMemsetAsync(ws, 0, 0x4020, stream);               // flagsIC + cnt
  hipLaunchKernelGGL(k_convert, dim3(9216),    dim3(256), 0, stream, w_ih, x, wihbf, comb);
  hipLaunchKernelGGL(k_qkv,     dim3(12, 512), dim3(256), 0, stream, comb, in_w, in_b, qbuf, kbuf, vbuf);
  hipLaunchKernelGGL(k_attn,    dim3(512),     dim3(256), 0, stream, qbuf, kbuf, vbuf, ctx);
  hipLaunchKernelGGL(k_outproj, dim3(4, 512),  dim3(256), 0, stream, ctx, mo_w, mo_b, comb);
  hipLaunchKernelGGL(k_gates,   dim3(16, 256), dim3(256), 0, stream, comb, wihbf, b_ih, b_hh, gates);
  hipMemsetAsync(comb, 0, 0x10000, stream);  // h-ring slot 0 = h(-1) = zeros (comb dead now)
  hipLaunchKernelGGL(k_lstm,    dim3(512),     dim3(256), 0, stream, w_hh, gates, comb, pooled, flagsIC, flr, cnt);
  hipLaunchKernelGGL(k_final,   dim3(64),      dim3(256), 0, stream, pooled, proj_w, proj_b, (float*)d_out);
}

// Round 8
// 1944.691 us; speedup vs baseline: 2.0194x; 1.0997x over previous
//
#include <hip/hip_runtime.h>
#include <hip/hip_bf16.h>
#include <stdint.h>

// Problem: S=512, N=64, E=256, NH=8, HD=32, LH=512.
// Pipeline: convert -> qkv -> attn -> outproj -> gates GEMM -> persistent LSTM -> final proj.
// R14 = R10 (best measured: 1370us k_lstm) with two surgical cuts to its serial chain.
// Lesson bank: R9 (fence-in-poll) -3x; R11 (optimistic read) -2.5x: consumers are
// SYSTEMATICALLY early, the wait must exist. R12 (role-split poll) and R13 (all-wave
// poll, 0 barriers) both regressed: barriers are cheap when waves are waiting anyway;
// poll must stay wave-0-only, right before the data is needed. R10's schedule is kept
// EXACTLY; changes only:
//  (1) EARLY PUBLISH: producer waves 0-1 drain their OWN h stores (per-wave
//      s_waitcnt vmcnt(0)) and emit flags immediately — not after barrier3's all-wave
//      rendezvous. Flag-implies-h per wave; flr word packs both wave-bytes (u16),
//      consumer requires 0x0101. IC fallback split into 2 per-slot flags (one per
//      producer wave) so the rare path can't see wave0's flag before wave1's h.
//  (2) barrier3 DELETED via Dg[2] double-buffer (st&1) — the R12 sub-mechanism that
//      was provably correct. barrier2 alone orders Dg across steps: wave w's Dg[p]
//      write at st+2 is after barrier2(st+1), which waves 0-1 enter only after their
//      Dg[p] reads at st completed (program order).
//  (3) 16 fresh-address u16 replicas (same 4MB flr footprint as R10's 8xu32).
// Kept: poll-first ordering, areg burst + 4 MFMA chains, nx prefetch post-poll,
// v_rcp elementwise.

typedef __attribute__((ext_vector_type(8))) short bf16x8;
typedef __attribute__((ext_vector_type(4))) float f32x4;

__device__ __forceinline__ unsigned short f2bf(float f){
  unsigned u = __float_as_uint(f);
  u += 0x7FFFu + ((u >> 16) & 1u);          // RNE
  return (unsigned short)(u >> 16);
}
__device__ __forceinline__ float b2f(unsigned short h){
  return __uint_as_float(((unsigned)h) << 16);
}
__device__ __forceinline__ ushort4 f4tobf(float4 f){
  ushort4 o; o.x=f2bf(f.x); o.y=f2bf(f.y); o.z=f2bf(f.z); o.w=f2bf(f.w); return o;
}

// ---------------- workspace layout (bytes) ----------------
// flagsIC:  [0x0,      0x4000)   (g*32+slot)*16 + wave*8 : 2 IC flags per slot
// cnt:      [0x4000,   0x4020)   8 ints, per-XCD slot claim
// pooled:   [0x30000,  0x50000)  64x512 f32
// w_ih bf16:[0x50000,  0x250000)
// flr:      [0x300000, 0x700000) u16 replica flags: [st][r<16][g][slot], bytes = waves 0/1
// combined: [0x800000, 0x2800000) 32768x512 bf16; REUSED by k_lstm as h-ring:
//           ring[st][g] = 8KB (8 batches x 512 units bf16), 64KB/step, 32MB total
// gates:    [0x3000000,0xB000000) layout [m][u][gate] = m*2048 + u*4 + gate (aliases q/k/v/ctx)
// q:0x3000000 k:0x4000000 v:0x5000000 ctx:0x6000000 (each 16MB bf16)
// total required ws: 0xB000000 = 184,549,376 B

// K0: w_ih fp32->bf16, and x fp32 -> combined[:, 0:256] bf16
__global__ __launch_bounds__(256) void k_convert(const float* __restrict__ wih,
                                                 const float* __restrict__ x,
                                                 unsigned short* __restrict__ wih_bf,
                                                 unsigned short* __restrict__ comb){
  size_t i = ((size_t)blockIdx.x * 256 + threadIdx.x) * 4;
  if (i < 1048576){
    float4 f = *(const float4*)(wih + i);
    *(ushort4*)(wih_bf + i) = f4tobf(f);
  } else {
    size_t j = i - 1048576;
    if (j < 8388608){
      float4 f = *(const float4*)(x + j);
      size_t m = j >> 8, c = j & 255;
      *(ushort4*)(comb + m*512 + c) = f4tobf(f);
    }
  }
}

// K1: qkv = x @ in_proj_w.T + b ; scale folded into q; writes q/k [n][h][s][d], v transposed [n][h][d][s]
__global__ __launch_bounds__(256) void k_qkv(const unsigned short* __restrict__ xb,
                                             const float* __restrict__ w,
                                             const float* __restrict__ bias,
                                             unsigned short* __restrict__ q,
                                             unsigned short* __restrict__ kk,
                                             unsigned short* __restrict__ v){
  const int nt = blockIdx.x;    // 0..11
  const int mt = blockIdx.y;    // 0..511  (= s, since M-row = s*64+n)
  __shared__ unsigned short Bs[64][264];
  const int t = threadIdx.x;
  { // stage+convert B tile (in_proj_w rows nt*64..+64, k 0..256)
    int row = t >> 2, c0 = (t & 3) * 64;
    const float* src = w + (size_t)(nt*64 + row)*256 + c0;
    #pragma unroll
    for (int i = 0; i < 64; i += 4){
      float4 f = *(const float4*)(src + i);
      *(ushort4*)&Bs[row][c0 + i] = f4tobf(f);
    }
  }
  __syncthreads();
  const int w4 = t >> 6, l = t & 63, lr = l & 15, lc = l >> 4;
  f32x4 acc[4];
  #pragma unroll
  for (int i = 0; i < 4; ++i) acc[i] = (f32x4){0.f,0.f,0.f,0.f};
  const size_t arow = (size_t)(mt*64 + w4*16 + lr) * 512;  // A from combined (bf16 x)
  #pragma unroll
  for (int kt = 0; kt < 8; ++kt){
    bf16x8 a = *(const bf16x8*)(xb + arow + kt*32 + lc*8);
    #pragma unroll
    for (int n4 = 0; n4 < 4; ++n4){
      bf16x8 b = *(const bf16x8*)&Bs[n4*16 + lr][kt*32 + lc*8];
      acc[n4] = __builtin_amdgcn_mfma_f32_16x16x32_bf16(a, b, acc[n4], 0, 0, 0);
    }
  }
  const int s = mt;
  #pragma unroll
  for (int n4 = 0; n4 < 4; ++n4){
    int ncol = nt*64 + n4*16 + lr;
    float bv = bias[ncol];
    int which = ncol >> 8, rem = ncol & 255, hh = rem >> 5, d = rem & 31;
    #pragma unroll
    for (int reg = 0; reg < 4; ++reg){
      int nb = w4*16 + lc*4 + reg;   // batch
      float val = acc[n4][reg] + bv;
      if (which == 0){
        val *= 0.17677669529663687f;  // 1/sqrt(32)
        q[((size_t)(nb*8 + hh)*512 + s)*32 + d] = f2bf(val);
      } else if (which == 1){
        kk[((size_t)(nb*8 + hh)*512 + s)*32 + d] = f2bf(val);
      } else {
        v[((size_t)(nb*8 + hh)*32 + d)*512 + s] = f2bf(val);
      }
    }
  }
}

// K2: attention for one (n,h); Q-tile=32, full-S bf16 score strip in LDS, exp recomputed into PV A-frags
__global__ __launch_bounds__(256) void k_attn(const unsigned short* __restrict__ q,
                                              const unsigned short* __restrict__ k,
                                              const unsigned short* __restrict__ v,
                                              unsigned short* __restrict__ ctx){
  const int nh = blockIdx.x;
  const int n = nh >> 3, h = nh & 7;
  __shared__ unsigned short sc[32][520];
  __shared__ float red[32][8];
  __shared__ float rowmax[32], rowinv[32];
  const unsigned short* qb = q + (size_t)nh * 512 * 32;
  const unsigned short* kb = k + (size_t)nh * 512 * 32;
  const unsigned short* vb = v + (size_t)nh * 32 * 512;
  const int t = threadIdx.x, w4 = t >> 6, l = t & 63, lr = l & 15, lc = l >> 4;
  const int r = t >> 3, cc = t & 7;
  for (int qt = 0; qt < 16; ++qt){
    const int s0 = qt * 32;
    bf16x8 aq0 = *(const bf16x8*)(qb + (size_t)(s0 + lr)*32 + lc*8);
    bf16x8 aq1 = *(const bf16x8*)(qb + (size_t)(s0 + 16 + lr)*32 + lc*8);
    #pragma unroll
    for (int j = 0; j < 8; ++j){
      int ntl = w4*8 + j;
      bf16x8 bk = *(const bf16x8*)(kb + (size_t)(ntl*16 + lr)*32 + lc*8);
      f32x4 d0 = (f32x4){0.f,0.f,0.f,0.f}, d1 = (f32x4){0.f,0.f,0.f,0.f};
      d0 = __builtin_amdgcn_mfma_f32_16x16x32_bf16(aq0, bk, d0, 0, 0, 0);
      d1 = __builtin_amdgcn_mfma_f32_16x16x32_bf16(aq1, bk, d1, 0, 0, 0);
      #pragma unroll
      for (int reg = 0; reg < 4; ++reg){
        sc[lc*4 + reg][ntl*16 + lr]      = f2bf(d0[reg]);
        sc[16 + lc*4 + reg][ntl*16 + lr] = f2bf(d1[reg]);
      }
    }
    __syncthreads();
    float pm = -1e30f;
    for (int i = 0; i < 64; ++i) pm = fmaxf(pm, b2f(sc[r][cc + 8*i]));
    red[r][cc] = pm;
    __syncthreads();
    float mfull = red[r][0];
    #pragma unroll
    for (int i = 1; i < 8; ++i) mfull = fmaxf(mfull, red[r][i]);
    rowmax[r] = mfull;   // benign same-value race across the 8 threads of a row
    __syncthreads();
    float sum = 0.f;
    for (int i = 0; i < 64; ++i) sum += __expf(b2f(sc[r][cc + 8*i]) - mfull);
    red[r][cc] = sum;
    __syncthreads();
    float ss = 0.f;
    #pragma unroll
    for (int i = 0; i < 8; ++i) ss += red[r][i];
    rowinv[r] = 1.f / ss;
    __syncthreads();
    // PV: each wave one 16x16 tile of the 32x32 O
    const int mt = w4 >> 1, ntd = w4 & 1;
    const int arow = mt*16 + lr;
    const float mrow = rowmax[arow];
    f32x4 o = (f32x4){0.f,0.f,0.f,0.f};
    for (int kt = 0; kt < 16; ++kt){
      bf16x8 sv = *(const bf16x8*)&sc[arow][kt*32 + lc*8];
      bf16x8 ap;
      #pragma unroll
      for (int e = 0; e < 8; ++e){
        float p = __expf(b2f((unsigned short)sv[e]) - mrow);
        ap[e] = (short)f2bf(p);
      }
      bf16x8 bv = *(const bf16x8*)(vb + (size_t)(ntd*16 + lr)*512 + kt*32 + lc*8);
      o = __builtin_amdgcn_mfma_f32_16x16x32_bf16(ap, bv, o, 0, 0, 0);
    }
    #pragma unroll
    for (int reg = 0; reg < 4; ++reg){
      int row = mt*16 + lc*4 + reg;
      int d = ntd*16 + lr;
      float val = o[reg] * rowinv[row];
      ctx[((size_t)(s0 + row)*64 + n)*256 + h*32 + d] = f2bf(val);
    }
    __syncthreads();
  }
}

// K3: attn_out = ctx @ mha_out_w.T + b -> combined[:, 256:512]
__global__ __launch_bounds__(256) void k_outproj(const unsigned short* __restrict__ ctx,
                                                 const float* __restrict__ w,
                                                 const float* __restrict__ bias,
                                                 unsigned short* __restrict__ comb){
  const int nt = blockIdx.x;   // 0..3
  const int mt = blockIdx.y;   // 0..511
  __shared__ unsigned short Bs[64][264];
  const int t = threadIdx.x;
  {
    int row = t >> 2, c0 = (t & 3) * 64;
    const float* src = w + (size_t)(nt*64 + row)*256 + c0;
    #pragma unroll
    for (int i = 0; i < 64; i += 4){
      float4 f = *(const float4*)(src + i);
      *(ushort4*)&Bs[row][c0 + i] = f4tobf(f);
    }
  }
  __syncthreads();
  const int w4 = t >> 6, l = t & 63, lr = l & 15, lc = l >> 4;
  f32x4 acc[4];
  #pragma unroll
  for (int i = 0; i < 4; ++i) acc[i] = (f32x4){0.f,0.f,0.f,0.f};
  const size_t arow = (size_t)(mt*64 + w4*16 + lr) * 256;
  #pragma unroll
  for (int kt = 0; kt < 8; ++kt){
    bf16x8 a = *(const bf16x8*)(ctx + arow + kt*32 + lc*8);
    #pragma unroll
    for (int n4 = 0; n4 < 4; ++n4){
      bf16x8 b = *(const bf16x8*)&Bs[n4*16 + lr][kt*32 + lc*8];
      acc[n4] = __builtin_amdgcn_mfma_f32_16x16x32_bf16(a, b, acc[n4], 0, 0, 0);
    }
  }
  #pragma unroll
  for (int n4 = 0; n4 < 4; ++n4){
    int ncol = nt*64 + n4*16 + lr;
    float bv = bias[ncol];
    #pragma unroll
    for (int reg = 0; reg < 4; ++reg){
      int m = mt*64 + w4*16 + lc*4 + reg;
      comb[(size_t)m*512 + 256 + ncol] = f2bf(acc[n4][reg] + bv);
    }
  }
}

// K4: gates_x = combined @ w_ih.T + (b_ih + b_hh), 128x128 tiles, BK=64.
// Output layout for k_lstm: gates[m][u][gate] = m*2048 + u*4 + gate  (m = st*64 + n).
__global__ __launch_bounds__(256) void k_gates(const unsigned short* __restrict__ A,
                                               const unsigned short* __restrict__ B,
                                               const float* __restrict__ bih,
                                               const float* __restrict__ bhh,
                                               unsigned short* __restrict__ gates){
  const int ntile = blockIdx.x;  // 0..15
  const int mtile = blockIdx.y;  // 0..255
  __shared__ unsigned short As[128][72], Bss[128][72];
  const int t = threadIdx.x, w4 = t >> 6, l = t & 63, lr = l & 15, lc = l >> 4;
  const int wm = w4 >> 1, wn = w4 & 1;
  f32x4 acc[4][4];
  #pragma unroll
  for (int i = 0; i < 4; ++i)
    #pragma unroll
    for (int j = 0; j < 4; ++j) acc[i][j] = (f32x4){0.f,0.f,0.f,0.f};
  const int srow = t >> 1, half = t & 1;
  const unsigned short* sa = A + (size_t)(mtile*128 + srow)*512 + half*32;
  const unsigned short* sb = B + (size_t)(ntile*128 + srow)*512 + half*32;
  for (int kkk = 0; kkk < 8; ++kkk){
    #pragma unroll
    for (int i = 0; i < 4; ++i){
      *(uint4*)&As [srow][half*32 + i*8] = *(const uint4*)(sa + kkk*64 + i*8);
      *(uint4*)&Bss[srow][half*32 + i*8] = *(const uint4*)(sb + kkk*64 + i*8);
    }
    __syncthreads();
    #pragma unroll
    for (int kt = 0; kt < 2; ++kt){
      bf16x8 af[4], bfr[4];
      #pragma unroll
      for (int i = 0; i < 4; ++i) af[i]  = *(const bf16x8*)&As [wm*64 + i*16 + lr][kt*32 + lc*8];
      #pragma unroll
      for (int i = 0; i < 4; ++i) bfr[i] = *(const bf16x8*)&Bss[wn*64 + i*16 + lr][kt*32 + lc*8];
      #pragma unroll
      for (int i = 0; i < 4; ++i)
        #pragma unroll
        for (int j = 0; j < 4; ++j)
          acc[i][j] = __builtin_amdgcn_mfma_f32_16x16x32_bf16(af[i], bfr[j], acc[i][j], 0, 0, 0);
    }
    __syncthreads();
  }
  #pragma unroll
  for (int i = 0; i < 4; ++i){
    #pragma unroll
    for (int j = 0; j < 4; ++j){
      int ncol = ntile*128 + wn*64 + j*16 + lr;
      int gate = ncol >> 9, u = ncol & 511;
      float bsum = bih[ncol] + bhh[ncol];
      #pragma unroll
      for (int reg = 0; reg < 4; ++reg){
        int m = mtile*128 + wm*64 + i*16 + lc*4 + reg;
        gates[(size_t)m*2048 + u*4 + gate] = f2bf(acc[i][j][reg] + bsum);
      }
    }
  }
}

// K5: persistent LSTM, XCD-local. Launch 512 WGs; ~88KB LDS -> 1 WG/CU, 32/XCD.
// Claim: g = physical XCC_ID, slot = atomicAdd(cnt[g]); slot>=32 -> exit.
// R14: R10 schedule + early per-wave publish + Dg double-buffer (no barrier3) + 16 u16 replicas.
__global__ __launch_bounds__(256, 1) void k_lstm(const float* __restrict__ whh,
                                                 const unsigned short* __restrict__ gates,
                                                 unsigned short* __restrict__ ring,
                                                 float* __restrict__ pooled,
                                                 int* __restrict__ flagsIC,
                                                 unsigned short* __restrict__ flr,
                                                 int* __restrict__ cnt){
  __shared__ unsigned short Wl[64][512];   // 64KB: rows = gate*16+unit
  __shared__ f32x4 Dg[2][4*2*16];          // 4KB: double-buffered by st&1
  __shared__ float padlds[5120];           // 20KB pad -> ~88KB total -> 1 WG/CU
  __shared__ int s_hdr[2];
  const int t = threadIdx.x, w4 = t >> 6, l = t & 63, lr = l & 15, lc = l >> 4;
  if ((int)blockIdx.x == -1) ((volatile float*)padlds)[0] = 1.f;  // keep padlds
  if (t == 0){
    unsigned xcc;
    asm volatile("s_getreg_b32 %0, hwreg(HW_REG_XCC_ID)" : "=s"(xcc));
    s_hdr[0] = (int)(xcc & 7);
    s_hdr[1] = atomicAdd(&cnt[xcc & 7], 1);   // device-scope claim
  }
  __syncthreads();
  const int g = s_hdr[0], slot = s_hdr[1];
  if (slot >= 32) return;                  // spare WG: free the CU immediately
  const int j0 = slot * 16;
  { // stage w_hh slice fp32->bf16, chunk swizzle phys = logical ^ (row&7)
    const int row = t >> 2;
    const int gate = row >> 4, u = row & 15;
    const float* src = whh + (size_t)(gate*512 + j0 + u) * 512;
    const int cbase = (t & 3) * 16;
    #pragma unroll
    for (int i = 0; i < 16; ++i){
      const int lch = cbase + i;
      float4 f0 = *(const float4*)(src + lch*8);
      float4 f1 = *(const float4*)(src + lch*8 + 4);
      const int pch = lch ^ (row & 7);
      *(ushort4*)&Wl[row][pch*8]     = f4tobf(f0);
      *(ushort4*)&Wl[row][pch*8 + 4] = f4tobf(f1);
    }
  }
  const int eb = t >> 4, eu = t & 15;      // elementwise ownership, t<128: (batch, unit)
  float cst = 0.f, pool = 0.f;
  unsigned long long gx = 0, nx = 0;
  if (t < 128)
    gx = *(const unsigned long long*)(gates + (size_t)(g*8 + eb)*2048 + (j0 + eu)*4);
  __syncthreads();
  for (int st = 0; st < 512; ++st){
    if (st > 0){
      if (t < 32){
        // serial fresh-address replica walk (R10-proven pacing), u16 words:
        // byte0 = wave0 done, byte1 = wave1 done (each after its own vmcnt(0) drain).
        bool need = true;
        #pragma unroll 1
        for (int r = 0; r < 16 && need; ++r){
          unsigned v = ((volatile const unsigned short*)flr)[((st*16 + r)*8 + g)*32 + t];
          need = (bool)__any(v != 0x0101u);
        }
        if (need){
          int t2 = 0;   // IC fallback: both per-slot wave flags; bounded, never hangs
          for (;;){
            int v0 = __hip_atomic_load(&flagsIC[(g*32 + t)*16],     __ATOMIC_RELAXED, __HIP_MEMORY_SCOPE_AGENT);
            int v1 = __hip_atomic_load(&flagsIC[(g*32 + t)*16 + 8], __ATOMIC_RELAXED, __HIP_MEMORY_SCOPE_AGENT);
            if (!__any((v0 < st) | (v1 < st)) || ++t2 >= 20000) break;
          }
        }
      }
      __syncthreads();   // barrier 1: release all waves into the gated read
    }
    // h(st) @ Wl^T : A rows = 8 batches (lr&7, duplicated), wave w4 = gate w4.
    // areg L2 burst first, nx HBM prefetch LAST (completes under MFMA+elementwise).
    const unsigned short* ha = ring + (((size_t)st*8 + g) << 12) + (lr & 7)*512 + lc*8;
    bf16x8 areg[16];
    #pragma unroll
    for (int kt = 0; kt < 16; ++kt) areg[kt] = *(const bf16x8*)(ha + kt*32);
    if (st < 511 && t < 128)
      nx = *(const unsigned long long*)(gates + ((size_t)(st+1)*64 + g*8 + eb)*2048 + (j0 + eu)*4);
    f32x4 ac0 = (f32x4){0.f,0.f,0.f,0.f}, ac1 = (f32x4){0.f,0.f,0.f,0.f};
    f32x4 ac2 = (f32x4){0.f,0.f,0.f,0.f}, ac3 = (f32x4){0.f,0.f,0.f,0.f};
    #pragma unroll
    for (int kt = 0; kt < 16; kt += 4){
      bf16x8 b0 = *(const bf16x8*)&Wl[w4*16 + lr][(((kt  )*4 + lc) ^ (lr & 7)) * 8];
      bf16x8 b1 = *(const bf16x8*)&Wl[w4*16 + lr][(((kt+1)*4 + lc) ^ (lr & 7)) * 8];
      bf16x8 b2 = *(const bf16x8*)&Wl[w4*16 + lr][(((kt+2)*4 + lc) ^ (lr & 7)) * 8];
      bf16x8 b3 = *(const bf16x8*)&Wl[w4*16 + lr][(((kt+3)*4 + lc) ^ (lr & 7)) * 8];
      ac0 = __builtin_amdgcn_mfma_f32_16x16x32_bf16(areg[kt  ], b0, ac0, 0, 0, 0);
      ac1 = __builtin_amdgcn_mfma_f32_16x16x32_bf16(areg[kt+1], b1, ac1, 0, 0, 0);
      ac2 = __builtin_amdgcn_mfma_f32_16x16x32_bf16(areg[kt+2], b2, ac2, 0, 0, 0);
      ac3 = __builtin_amdgcn_mfma_f32_16x16x32_bf16(areg[kt+3], b3, ac3, 0, 0, 0);
    }
    f32x4 acc = (ac0 + ac1) + (ac2 + ac3);
    const int p = st & 1;
    if (lc < 2) Dg[p][(w4*2 + lc)*16 + lr] = acc;   // D: col=unit(lane&15), row=batch(lc*4+reg)
    __syncthreads();   // barrier 2: Dg[p] complete (also orders Dg[p] reuse at st+2)
    if (t < 128){
      union { unsigned long long q; unsigned short u[4]; } ga; ga.q = gx;
      const int dq = (eb >> 2)*16 + eu, dr = eb & 3;
      float gi = Dg[p][0*32 + dq][dr] + b2f(ga.u[0]);
      float gf = Dg[p][1*32 + dq][dr] + b2f(ga.u[1]);
      float gc = Dg[p][2*32 + dq][dr] + b2f(ga.u[2]);
      float go = Dg[p][3*32 + dq][dr] + b2f(ga.u[3]);
      float i_ = __builtin_amdgcn_rcpf(1.f + __expf(-gi));
      float f_ = __builtin_amdgcn_rcpf(1.f + __expf(-gf));
      float cg = fminf(fmaxf(gc, -20.f), 20.f);
      float e2 = __expf(2.f * cg);
      float g_ = 1.f - 2.f * __builtin_amdgcn_rcpf(e2 + 1.f);
      float o_ = __builtin_amdgcn_rcpf(1.f + __expf(-go));
      float cn = f_ * cst + i_ * g_;
      cst = cn;
      float ct = fminf(fmaxf(cn, -20.f), 20.f);
      float e2c = __expf(2.f * ct);
      float th = 1.f - 2.f * __builtin_amdgcn_rcpf(e2c + 1.f);
      float hh = o_ * th;
      pool += hh;
      if (st < 511){
        // plain write-through h store -> this XCD's L2
        ring[(((size_t)(st+1)*8 + g) << 12) + eb*512 + j0 + eu] = f2bf(hh);
        // EARLY PUBLISH: this wave's h drained in L2 before its flag bytes go out.
        asm volatile("s_waitcnt vmcnt(0)" ::: "memory");
        if (l < 16)   // 16 u16 replicas; byte w4 of each
          ((unsigned char*)flr)[(((((size_t)(st+1)*16 + l)*8 + g)*32 + slot) << 1) + w4] = 1;
        if (l == 0)
          __hip_atomic_store(&flagsIC[(g*32 + slot)*16 + w4*8], st + 1,
                             __ATOMIC_RELAXED, __HIP_MEMORY_SCOPE_AGENT);
      }
      gx = nx;
    }
    // no barrier 3: Dg double-buffer provides cross-step ordering
  }
  if (t < 128)
    pooled[(size_t)(g*8 + eb)*512 + j0 + eu] = pool * (1.f / 512.f);
}

// K6: out = log_sigmoid(pooled @ proj_w.T + proj_b)
__global__ __launch_bounds__(256) void k_final(const float* __restrict__ pooled,
                                               const float* __restrict__ w,
                                               const float* __restrict__ bias,
                                               float* __restrict__ out){
  const int n = blockIdx.x;
  __shared__ float pr[512];
  const int t = threadIdx.x;
  pr[t]       = pooled[(size_t)n*512 + t];
  pr[t + 256] = pooled[(size_t)n*512 + t + 256];
  __syncthreads();
  const float* wr = w + (size_t)t * 512;
  float s = bias[t];
  for (int i = 0; i < 512; i += 4){
    float4 f = *(const float4*)(wr + i);
    s += f.x*pr[i] + f.y*pr[i+1] + f.z*pr[i+2] + f.w*pr[i+3];
  }
  float rres = fminf(s, 0.f) - log1pf(__expf(-fabsf(s)));
  out[(size_t)n*256 + t] = rres;
}

extern "C" void kernel_launch(void* const* d_in, const int* in_sizes, int n_in,
                              void* d_out, int out_size, void* d_ws, size_t ws_size,
                              hipStream_t stream){
  const float* x      = (const float*)d_in[0];
  const float* in_w   = (const float*)d_in[1];
  const float* in_b   = (const float*)d_in[2];
  const float* mo_w   = (const float*)d_in[3];
  const float* mo_b   = (const float*)d_in[4];
  const float* w_ih   = (const float*)d_in[5];
  const float* w_hh   = (const float*)d_in[6];
  const float* b_ih   = (const float*)d_in[7];
  const float* b_hh   = (const float*)d_in[8];
  const float* proj_w = (const float*)d_in[9];
  const float* proj_b = (const float*)d_in[10];
  uint8_t* ws = (uint8_t*)d_ws;
  int*             flagsIC = (int*)(ws + 0x0);
  int*             cnt     = (int*)(ws + 0x4000);
  float*           pooled  = (float*)(ws + 0x30000);
  unsigned short*  wihbf   = (unsigned short*)(ws + 0x50000);
  unsigned short*  flr     = (unsigned short*)(ws + 0x300000);
  unsigned short*  comb    = (unsigned short*)(ws + 0x800000);  // doubles as h-ring in k_lstm
  unsigned short*  gates   = (unsigned short*)(ws + 0x3000000);
  unsigned short*  qbuf    = (unsigned short*)(ws + 0x3000000); // aliases gates (dead before k_gates)
  unsigned short*  kbuf    = (unsigned short*)(ws + 0x4000000);
  unsigned short*  vbuf    = (unsigned short*)(ws + 0x5000000);
  unsigned short*  ctx     = (unsigned short*)(ws + 0x6000000);

  hipMemsetAsync(ws + 0x300000, 0, 0x400000, stream);  // flr
  hipMemsetAsync(ws, 0, 0x4020, stream);               // flagsIC + cnt
  hipLaunchKernelGGL(k_convert, dim3(9216),    dim3(256), 0, stream, w_ih, x, wihbf, comb);
  hipLaunchKernelGGL(k_qkv,     dim3(12, 512), dim3(256), 0, stream, comb, in_w, in_b, qbuf, kbuf, vbuf);
  hipLaunchKernelGGL(k_attn,    dim3(512),     dim3(256), 0, stream, qbuf, kbuf, vbuf, ctx);
  hipLaunchKernelGGL(k_outproj, dim3(4, 512),  dim3(256), 0, stream, ctx, mo_w, mo_b, comb);
  hipLaunchKernelGGL(k_gates,   dim3(16, 256), dim3(256), 0, stream, comb, wihbf, b_ih, b_hh, gates);
  hipMemsetAsync(comb, 0, 0x10000, stream);  // h-ring slot 0 = h(-1) = zeros (comb dead now)
  hipLaunchKernelGGL(k_lstm,    dim3(512),     dim3(256), 0, stream, w_hh, gates, comb, pooled, flagsIC, flr, cnt);
  hipLaunchKernelGGL(k_final,   dim3(64),      dim3(256), 0, stream, pooled, proj_w, proj_b, (float*)d_out);
}

// Round 9
// 1774.320 us; speedup vs baseline: 2.2133x; 1.0960x over previous
//
#include <hip/hip_runtime.h>
#include <hip/hip_bf16.h>
#include <stdint.h>

// Problem: S=512, N=64, E=256, NH=8, HD=32, LH=512.
// Pipeline: convert -> qkv -> attn -> outproj -> gates GEMM -> persistent LSTM -> final proj.
// R15 = R10's k_lstm VERBATIM (proven best: 1370us; R11-R14 structural variants all
// regressed — the handshake is at its practical floor) + optimization of the ~463us
// OUTSIDE k_lstm:
//  - k_gates: m97-structure staging — __builtin_amdgcn_global_load_lds(16B) into linear
//    [128][64] LDS, XOR chunk-swizzle via pre-swizzled per-lane GLOBAL source (rule #21:
//    linear dest + inverse-swz source + swz read; same ^(lr&7) involution as k_lstm's Wl).
//    MFMA + epilogue untouched -> bit-identical output. Guide ladder: this staging step
//    alone was 517->874 TF.
//  - k_attn: vectorized softmax (8x b128 loads replace 64 scalar ds_read_u16 per pass);
//    sum pass writes exp'd P back into the score strip (same f32 exp, same f2bf rounding
//    -> bit-identical) so PV is pure LDS-read+MFMA (deletes 128 exp + 128 f2bf per
//    thread per qt). rowmax[] dead -> removed.

typedef __attribute__((ext_vector_type(8))) short bf16x8;
typedef __attribute__((ext_vector_type(4))) float f32x4;

__device__ __forceinline__ unsigned short f2bf(float f){
  unsigned u = __float_as_uint(f);
  u += 0x7FFFu + ((u >> 16) & 1u);          // RNE
  return (unsigned short)(u >> 16);
}
__device__ __forceinline__ float b2f(unsigned short h){
  return __uint_as_float(((unsigned)h) << 16);
}
__device__ __forceinline__ ushort4 f4tobf(float4 f){
  ushort4 o; o.x=f2bf(f.x); o.y=f2bf(f.y); o.z=f2bf(f.z); o.w=f2bf(f.w); return o;
}
// async global->LDS, 16B per lane: per-lane global src, wave-uniform LDS base (+lane*16).
__device__ __forceinline__ void gload_lds16(const void* g, void* l){
  __builtin_amdgcn_global_load_lds((const __attribute__((address_space(1))) unsigned int*)g,
                                   (__attribute__((address_space(3))) unsigned int*)l, 16, 0, 0);
}

// ---------------- workspace layout (bytes) ----------------
// flagsIC:  [0x0,      0x4000)   8 groups x 32 slots, 64B stride (IC fallback flags)
// cnt:      [0x4000,   0x4020)   8 ints, per-XCD slot claim
// pooled:   [0x30000,  0x50000)  64x512 f32
// w_ih bf16:[0x50000,  0x250000)
// flr:      [0x300000, 0x700000) replicated L2 flags: [st][r<8][g][slot] int, 4MB
// combined: [0x800000, 0x2800000) 32768x512 bf16; REUSED by k_lstm as h-ring:
//           ring[st][g] = 8KB (8 batches x 512 units bf16), 64KB/step, 32MB total
// gates:    [0x3000000,0xB000000) layout [m][u][gate] = m*2048 + u*4 + gate (aliases q/k/v/ctx)
// q:0x3000000 k:0x4000000 v:0x5000000 ctx:0x6000000 (each 16MB bf16)
// total required ws: 0xB000000 = 184,549,376 B

// K0: w_ih fp32->bf16, and x fp32 -> combined[:, 0:256] bf16
__global__ __launch_bounds__(256) void k_convert(const float* __restrict__ wih,
                                                 const float* __restrict__ x,
                                                 unsigned short* __restrict__ wih_bf,
                                                 unsigned short* __restrict__ comb){
  size_t i = ((size_t)blockIdx.x * 256 + threadIdx.x) * 4;
  if (i < 1048576){
    float4 f = *(const float4*)(wih + i);
    *(ushort4*)(wih_bf + i) = f4tobf(f);
  } else {
    size_t j = i - 1048576;
    if (j < 8388608){
      float4 f = *(const float4*)(x + j);
      size_t m = j >> 8, c = j & 255;
      *(ushort4*)(comb + m*512 + c) = f4tobf(f);
    }
  }
}

// K1: qkv = x @ in_proj_w.T + b ; scale folded into q; writes q/k [n][h][s][d], v transposed [n][h][d][s]
__global__ __launch_bounds__(256) void k_qkv(const unsigned short* __restrict__ xb,
                                             const float* __restrict__ w,
                                             const float* __restrict__ bias,
                                             unsigned short* __restrict__ q,
                                             unsigned short* __restrict__ kk,
                                             unsigned short* __restrict__ v){
  const int nt = blockIdx.x;    // 0..11
  const int mt = blockIdx.y;    // 0..511  (= s, since M-row = s*64+n)
  __shared__ unsigned short Bs[64][264];
  const int t = threadIdx.x;
  { // stage+convert B tile (in_proj_w rows nt*64..+64, k 0..256)
    int row = t >> 2, c0 = (t & 3) * 64;
    const float* src = w + (size_t)(nt*64 + row)*256 + c0;
    #pragma unroll
    for (int i = 0; i < 64; i += 4){
      float4 f = *(const float4*)(src + i);
      *(ushort4*)&Bs[row][c0 + i] = f4tobf(f);
    }
  }
  __syncthreads();
  const int w4 = t >> 6, l = t & 63, lr = l & 15, lc = l >> 4;
  f32x4 acc[4];
  #pragma unroll
  for (int i = 0; i < 4; ++i) acc[i] = (f32x4){0.f,0.f,0.f,0.f};
  const size_t arow = (size_t)(mt*64 + w4*16 + lr) * 512;  // A from combined (bf16 x)
  #pragma unroll
  for (int kt = 0; kt < 8; ++kt){
    bf16x8 a = *(const bf16x8*)(xb + arow + kt*32 + lc*8);
    #pragma unroll
    for (int n4 = 0; n4 < 4; ++n4){
      bf16x8 b = *(const bf16x8*)&Bs[n4*16 + lr][kt*32 + lc*8];
      acc[n4] = __builtin_amdgcn_mfma_f32_16x16x32_bf16(a, b, acc[n4], 0, 0, 0);
    }
  }
  const int s = mt;
  #pragma unroll
  for (int n4 = 0; n4 < 4; ++n4){
    int ncol = nt*64 + n4*16 + lr;
    float bv = bias[ncol];
    int which = ncol >> 8, rem = ncol & 255, hh = rem >> 5, d = rem & 31;
    #pragma unroll
    for (int reg = 0; reg < 4; ++reg){
      int nb = w4*16 + lc*4 + reg;   // batch
      float val = acc[n4][reg] + bv;
      if (which == 0){
        val *= 0.17677669529663687f;  // 1/sqrt(32)
        q[((size_t)(nb*8 + hh)*512 + s)*32 + d] = f2bf(val);
      } else if (which == 1){
        kk[((size_t)(nb*8 + hh)*512 + s)*32 + d] = f2bf(val);
      } else {
        v[((size_t)(nb*8 + hh)*32 + d)*512 + s] = f2bf(val);
      }
    }
  }
}

// K2: attention for one (n,h); Q-tile=32, full-S bf16 score strip in LDS.
// R15: vectorized softmax; P written back into sc during sum pass (bit-identical values);
// PV reads P directly — no exp recompute.
__global__ __launch_bounds__(256) void k_attn(const unsigned short* __restrict__ q,
                                              const unsigned short* __restrict__ k,
                                              const unsigned short* __restrict__ v,
                                              unsigned short* __restrict__ ctx){
  const int nh = blockIdx.x;
  const int n = nh >> 3, h = nh & 7;
  __shared__ unsigned short sc[32][520];
  __shared__ float red[32][8];
  __shared__ float rowinv[32];
  const unsigned short* qb = q + (size_t)nh * 512 * 32;
  const unsigned short* kb = k + (size_t)nh * 512 * 32;
  const unsigned short* vb = v + (size_t)nh * 32 * 512;
  const int t = threadIdx.x, w4 = t >> 6, l = t & 63, lr = l & 15, lc = l >> 4;
  const int r = t >> 3, cc = t & 7;
  for (int qt = 0; qt < 16; ++qt){
    const int s0 = qt * 32;
    bf16x8 aq0 = *(const bf16x8*)(qb + (size_t)(s0 + lr)*32 + lc*8);
    bf16x8 aq1 = *(const bf16x8*)(qb + (size_t)(s0 + 16 + lr)*32 + lc*8);
    #pragma unroll
    for (int j = 0; j < 8; ++j){
      int ntl = w4*8 + j;
      bf16x8 bk = *(const bf16x8*)(kb + (size_t)(ntl*16 + lr)*32 + lc*8);
      f32x4 d0 = (f32x4){0.f,0.f,0.f,0.f}, d1 = (f32x4){0.f,0.f,0.f,0.f};
      d0 = __builtin_amdgcn_mfma_f32_16x16x32_bf16(aq0, bk, d0, 0, 0, 0);
      d1 = __builtin_amdgcn_mfma_f32_16x16x32_bf16(aq1, bk, d1, 0, 0, 0);
      #pragma unroll
      for (int reg = 0; reg < 4; ++reg){
        sc[lc*4 + reg][ntl*16 + lr]      = f2bf(d0[reg]);
        sc[16 + lc*4 + reg][ntl*16 + lr] = f2bf(d1[reg]);
      }
    }
    __syncthreads();
    // max pass: thread (r,cc) owns chunks {i*8+cc} (8 x 8 cols, disjoint, b128 loads)
    float pm = -1e30f;
    #pragma unroll
    for (int i = 0; i < 8; ++i){
      bf16x8 vv = *(const bf16x8*)&sc[r][(i*8 + cc)*8];
      #pragma unroll
      for (int e = 0; e < 8; ++e) pm = fmaxf(pm, b2f((unsigned short)vv[e]));
    }
    red[r][cc] = pm;
    __syncthreads();
    float mfull = red[r][0];
    #pragma unroll
    for (int i = 1; i < 8; ++i) mfull = fmaxf(mfull, red[r][i]);
    __syncthreads();
    // sum pass + P writeback (same chunks; same f32 exp and f2bf rounding as before)
    float sum = 0.f;
    #pragma unroll
    for (int i = 0; i < 8; ++i){
      bf16x8 vv = *(const bf16x8*)&sc[r][(i*8 + cc)*8];
      bf16x8 pv;
      #pragma unroll
      for (int e = 0; e < 8; ++e){
        float p = __expf(b2f((unsigned short)vv[e]) - mfull);
        sum += p;
        pv[e] = (short)f2bf(p);
      }
      *(bf16x8*)&sc[r][(i*8 + cc)*8] = pv;
    }
    red[r][cc] = sum;
    __syncthreads();
    float ss = 0.f;
    #pragma unroll
    for (int i = 0; i < 8; ++i) ss += red[r][i];
    rowinv[r] = 1.f / ss;
    __syncthreads();
    // PV: each wave one 16x16 tile of the 32x32 O; A-frags = P directly from LDS
    const int mt = w4 >> 1, ntd = w4 & 1;
    const int arow = mt*16 + lr;
    f32x4 o = (f32x4){0.f,0.f,0.f,0.f};
    for (int kt = 0; kt < 16; ++kt){
      bf16x8 ap = *(const bf16x8*)&sc[arow][kt*32 + lc*8];
      bf16x8 bv = *(const bf16x8*)(vb + (size_t)(ntd*16 + lr)*512 + kt*32 + lc*8);
      o = __builtin_amdgcn_mfma_f32_16x16x32_bf16(ap, bv, o, 0, 0, 0);
    }
    #pragma unroll
    for (int reg = 0; reg < 4; ++reg){
      int row = mt*16 + lc*4 + reg;
      int d = ntd*16 + lr;
      float val = o[reg] * rowinv[row];
      ctx[((size_t)(s0 + row)*64 + n)*256 + h*32 + d] = f2bf(val);
    }
    __syncthreads();
  }
}

// K3: attn_out = ctx @ mha_out_w.T + b -> combined[:, 256:512]
__global__ __launch_bounds__(256) void k_outproj(const unsigned short* __restrict__ ctx,
                                                 const float* __restrict__ w,
                                                 const float* __restrict__ bias,
                                                 unsigned short* __restrict__ comb){
  const int nt = blockIdx.x;   // 0..3
  const int mt = blockIdx.y;   // 0..511
  __shared__ unsigned short Bs[64][264];
  const int t = threadIdx.x;
  {
    int row = t >> 2, c0 = (t & 3) * 64;
    const float* src = w + (size_t)(nt*64 + row)*256 + c0;
    #pragma unroll
    for (int i = 0; i < 64; i += 4){
      float4 f = *(const float4*)(src + i);
      *(ushort4*)&Bs[row][c0 + i] = f4tobf(f);
    }
  }
  __syncthreads();
  const int w4 = t >> 6, l = t & 63, lr = l & 15, lc = l >> 4;
  f32x4 acc[4];
  #pragma unroll
  for (int i = 0; i < 4; ++i) acc[i] = (f32x4){0.f,0.f,0.f,0.f};
  const size_t arow = (size_t)(mt*64 + w4*16 + lr) * 256;
  #pragma unroll
  for (int kt = 0; kt < 8; ++kt){
    bf16x8 a = *(const bf16x8*)(ctx + arow + kt*32 + lc*8);
    #pragma unroll
    for (int n4 = 0; n4 < 4; ++n4){
      bf16x8 b = *(const bf16x8*)&Bs[n4*16 + lr][kt*32 + lc*8];
      acc[n4] = __builtin_amdgcn_mfma_f32_16x16x32_bf16(a, b, acc[n4], 0, 0, 0);
    }
  }
  #pragma unroll
  for (int n4 = 0; n4 < 4; ++n4){
    int ncol = nt*64 + n4*16 + lr;
    float bv = bias[ncol];
    #pragma unroll
    for (int reg = 0; reg < 4; ++reg){
      int m = mt*64 + w4*16 + lc*4 + reg;
      comb[(size_t)m*512 + 256 + ncol] = f2bf(acc[n4][reg] + bv);
    }
  }
}

// K4: gates_x = combined @ w_ih.T + (b_ih + b_hh), 128x128 tiles, BK=64.
// R15: m97-style staging — global_load_lds(16B) into linear [128][64] LDS; XOR chunk
// swizzle (^(row&7), row&7 == lane>>3 on stage, == lr&7 on read) applied on the GLOBAL
// source and on the LDS read (rule #21). MFMA + epilogue identical to R10.
// Output layout for k_lstm: gates[m][u][gate] = m*2048 + u*4 + gate  (m = st*64 + n).
__global__ __launch_bounds__(256) void k_gates(const unsigned short* __restrict__ A,
                                               const unsigned short* __restrict__ B,
                                               const float* __restrict__ bih,
                                               const float* __restrict__ bhh,
                                               unsigned short* __restrict__ gates){
  const int ntile = blockIdx.x;  // 0..15
  const int mtile = blockIdx.y;  // 0..255
  __shared__ unsigned short As[128][64], Bss[128][64];
  const int t = threadIdx.x, w4 = t >> 6, l = t & 63, lr = l & 15, lc = l >> 4;
  const int wm = w4 >> 1, wn = w4 & 1;
  f32x4 acc[4][4];
  #pragma unroll
  for (int i = 0; i < 4; ++i)
    #pragma unroll
    for (int j = 0; j < 4; ++j) acc[i][j] = (f32x4){0.f,0.f,0.f,0.f};
  const int ch = (l & 7) ^ (l >> 3);       // inverse-swizzled global chunk for this lane
  for (int kkk = 0; kkk < 8; ++kkk){
    // stage: each wave 4 calls x 8 rows x 128B, linear LDS dest (base + lane*16)
    #pragma unroll
    for (int c = 0; c < 4; ++c){
      const int row = w4*32 + c*8 + (l >> 3);
      gload_lds16(A + (size_t)(mtile*128 + row)*512 + kkk*64 + ch*8, &As [w4*32 + c*8][0]);
      gload_lds16(B + (size_t)(ntile*128 + row)*512 + kkk*64 + ch*8, &Bss[w4*32 + c*8][0]);
    }
    __syncthreads();   // compiler drains vmcnt before s_barrier -> LDS tiles complete
    #pragma unroll
    for (int kt = 0; kt < 2; ++kt){
      bf16x8 af[4], bfr[4];
      #pragma unroll
      for (int i = 0; i < 4; ++i)
        af[i]  = *(const bf16x8*)&As [wm*64 + i*16 + lr][(((kt*4 + lc) ^ (lr & 7)) * 8)];
      #pragma unroll
      for (int i = 0; i < 4; ++i)
        bfr[i] = *(const bf16x8*)&Bss[wn*64 + i*16 + lr][(((kt*4 + lc) ^ (lr & 7)) * 8)];
      #pragma unroll
      for (int i = 0; i < 4; ++i)
        #pragma unroll
        for (int j = 0; j < 4; ++j)
          acc[i][j] = __builtin_amdgcn_mfma_f32_16x16x32_bf16(af[i], bfr[j], acc[i][j], 0, 0, 0);
    }
    __syncthreads();
  }
  #pragma unroll
  for (int i = 0; i < 4; ++i){
    #pragma unroll
    for (int j = 0; j < 4; ++j){
      int ncol = ntile*128 + wn*64 + j*16 + lr;
      int gate = ncol >> 9, u = ncol & 511;
      float bsum = bih[ncol] + bhh[ncol];
      #pragma unroll
      for (int reg = 0; reg < 4; ++reg){
        int m = mtile*128 + wm*64 + i*16 + lc*4 + reg;
        gates[(size_t)m*2048 + u*4 + gate] = f2bf(acc[i][j][reg] + bsum);
      }
    }
  }
}

// K5: persistent LSTM, XCD-local — R10 VERBATIM (best measured: 1370us).
// Launch 512 WGs; 86KB LDS -> 1 WG/CU, 32/XCD. Claim: g = physical XCC_ID,
// slot = atomicAdd(cnt[g]); slot>=32 -> exit.
// Handshake: replicated write-once L2 flags (fresh-address retries) + IC fallback.
__global__ __launch_bounds__(256, 1) void k_lstm(const float* __restrict__ whh,
                                                 const unsigned short* __restrict__ gates,
                                                 unsigned short* __restrict__ ring,
                                                 float* __restrict__ pooled,
                                                 int* __restrict__ flagsIC,
                                                 int* __restrict__ flr,
                                                 int* __restrict__ cnt){
  __shared__ unsigned short Wl[64][512];   // 64KB: rows = gate*16+unit
  __shared__ f32x4 Dg[4*2*16];             // 2KB:  [gate][lc][unit]
  __shared__ float padlds[5120];           // 20KB pad -> 86KB total -> 1 WG/CU
  __shared__ int s_hdr[2];
  const int t = threadIdx.x, w4 = t >> 6, l = t & 63, lr = l & 15, lc = l >> 4;
  if ((int)blockIdx.x == -1) ((volatile float*)padlds)[0] = 1.f;  // keep padlds
  if (t == 0){
    unsigned xcc;
    asm volatile("s_getreg_b32 %0, hwreg(HW_REG_XCC_ID)" : "=s"(xcc));
    int g = (int)(xcc & 7);
    s_hdr[0] = g;
    s_hdr[1] = atomicAdd(&cnt[g], 1);      // device-scope claim
  }
  __syncthreads();
  const int g = s_hdr[0], slot = s_hdr[1];
  if (slot >= 32) return;                  // spare WG: free the CU immediately
  const int j0 = slot * 16;
  { // stage w_hh slice fp32->bf16, chunk swizzle phys = logical ^ (row&7)
    const int row = t >> 2;
    const int gate = row >> 4, u = row & 15;
    const float* src = whh + (size_t)(gate*512 + j0 + u) * 512;
    const int cbase = (t & 3) * 16;
    #pragma unroll
    for (int i = 0; i < 16; ++i){
      const int lch = cbase + i;
      float4 f0 = *(const float4*)(src + lch*8);
      float4 f1 = *(const float4*)(src + lch*8 + 4);
      const int pch = lch ^ (row & 7);
      *(ushort4*)&Wl[row][pch*8]     = f4tobf(f0);
      *(ushort4*)&Wl[row][pch*8 + 4] = f4tobf(f1);
    }
  }
  const int eb = t >> 4, eu = t & 15;      // elementwise ownership, t<128: (batch, unit)
  float cst = 0.f, pool = 0.f;
  unsigned long long gx = 0, nx = 0;
  if (t < 128)
    gx = *(const unsigned long long*)(gates + (size_t)(g*8 + eb)*2048 + (j0 + eu)*4);
  int* const myflagIC = &flagsIC[(g*32 + slot)*16];
  __syncthreads();
  for (int st = 0; st < 512; ++st){
    if (st > 0){
      if (t < 32){
        // L2 fast poll: retry r reads replica r -> fresh L1 line every attempt ->
        // served by the local XCD L2 where peers' plain flag stores land.
        bool need = true;
        #pragma unroll 1
        for (int r = 0; r < 8 && need; ++r){
          int v = ((volatile const int*)flr)[((st*8 + r)*8 + g)*32 + (t & 31)];
          need = (bool)__any(v == 0);
        }
        if (need){
          // pathological skew: proven IC atomic poll (bounded, correct-by-delay)
          int* fp = &flagsIC[(g*32 + (t & 31))*16];
          int t2 = 0;
          while (__hip_atomic_load(fp, __ATOMIC_RELAXED, __HIP_MEMORY_SCOPE_AGENT) < st
                 && ++t2 < 5000) { }
        }
      }
      __syncthreads();
    }
    // h(st) @ Wl^T : A rows = 8 batches (lr&7, duplicated), wave w4 = gate w4.
    // areg L2 burst first, nx HBM prefetch LAST (completes under MFMA+elementwise).
    const unsigned short* ha = ring + (((size_t)st*8 + g) << 12) + (lr & 7)*512 + lc*8;
    bf16x8 areg[16];
    #pragma unroll
    for (int kt = 0; kt < 16; ++kt) areg[kt] = *(const bf16x8*)(ha + kt*32);
    if (st < 511 && t < 128)
      nx = *(const unsigned long long*)(gates + ((size_t)(st+1)*64 + g*8 + eb)*2048 + (j0 + eu)*4);
    f32x4 acc0 = (f32x4){0.f,0.f,0.f,0.f}, acc1 = (f32x4){0.f,0.f,0.f,0.f};
    #pragma unroll
    for (int kt = 0; kt < 16; kt += 2){
      bf16x8 b0 = *(const bf16x8*)&Wl[w4*16 + lr][(((kt  )*4 + lc) ^ (lr & 7)) * 8];
      bf16x8 b1 = *(const bf16x8*)&Wl[w4*16 + lr][(((kt+1)*4 + lc) ^ (lr & 7)) * 8];
      acc0 = __builtin_amdgcn_mfma_f32_16x16x32_bf16(areg[kt],   b0, acc0, 0, 0, 0);
      acc1 = __builtin_amdgcn_mfma_f32_16x16x32_bf16(areg[kt+1], b1, acc1, 0, 0, 0);
    }
    f32x4 acc = acc0 + acc1;
    if (lc < 2) Dg[(w4*2 + lc)*16 + lr] = acc;   // D: col=unit(lane&15), row=batch(lc*4+reg)
    __syncthreads();
    if (t < 128){
      union { unsigned long long q; unsigned short u[4]; } ga; ga.q = gx;
      const int dq = (eb >> 2)*16 + eu, dr = eb & 3;
      float gi = Dg[0*32 + dq][dr] + b2f(ga.u[0]);
      float gf = Dg[1*32 + dq][dr] + b2f(ga.u[1]);
      float gc = Dg[2*32 + dq][dr] + b2f(ga.u[2]);
      float go = Dg[3*32 + dq][dr] + b2f(ga.u[3]);
      float i_ = __builtin_amdgcn_rcpf(1.f + __expf(-gi));
      float f_ = __builtin_amdgcn_rcpf(1.f + __expf(-gf));
      float cg = fminf(fmaxf(gc, -20.f), 20.f);
      float e2 = __expf(2.f * cg);
      float g_ = 1.f - 2.f * __builtin_amdgcn_rcpf(e2 + 1.f);
      float o_ = __builtin_amdgcn_rcpf(1.f + __expf(-go));
      float cn = f_ * cst + i_ * g_;
      cst = cn;
      float ct = fminf(fmaxf(cn, -20.f), 20.f);
      float e2c = __expf(2.f * ct);
      float th = 1.f - 2.f * __builtin_amdgcn_rcpf(e2c + 1.f);
      float hh = o_ * th;
      pool += hh;
      if (st < 511)  // plain write-through store -> lands in this XCD's L2
        ring[(((size_t)(st+1)*8 + g) << 12) + eb*512 + j0 + eu] = f2bf(hh);
      gx = nx;
    }
    __syncthreads();   // pre-barrier vmcnt(0) drains h stores to L2 [m97-measured semantics]
    if (st < 511){
      // h(st+1) in L2 now. Notify: 8 write-once L2 replicas (flag-in-L2 => h-in-L2,
      // same cache) + 1 IC flag for the fallback path.
      if (t < 8) flr[(((st+1)*8 + t)*8 + g)*32 + slot] = 1;
      if (t == 0) __hip_atomic_store(myflagIC, st + 1, __ATOMIC_RELAXED, __HIP_MEMORY_SCOPE_AGENT);
    }
  }
  if (t < 128)
    pooled[(size_t)(g*8 + eb)*512 + j0 + eu] = pool * (1.f / 512.f);
}

// K6: out = log_sigmoid(pooled @ proj_w.T + proj_b)
__global__ __launch_bounds__(256) void k_final(const float* __restrict__ pooled,
                                               const float* __restrict__ w,
                                               const float* __restrict__ bias,
                                               float* __restrict__ out){
  const int n = blockIdx.x;
  __shared__ float pr[512];
  const int t = threadIdx.x;
  pr[t]       = pooled[(size_t)n*512 + t];
  pr[t + 256] = pooled[(size_t)n*512 + t + 256];
  __syncthreads();
  const float* wr = w + (size_t)t * 512;
  float s = bias[t];
  for (int i = 0; i < 512; i += 4){
    float4 f = *(const float4*)(wr + i);
    s += f.x*pr[i] + f.y*pr[i+1] + f.z*pr[i+2] + f.w*pr[i+3];
  }
  float rres = fminf(s, 0.f) - log1pf(__expf(-fabsf(s)));
  out[(size_t)n*256 + t] = rres;
}

extern "C" void kernel_launch(void* const* d_in, const int* in_sizes, int n_in,
                              void* d_out, int out_size, void* d_ws, size_t ws_size,
                              hipStream_t stream){
  const float* x      = (const float*)d_in[0];
  const float* in_w   = (const float*)d_in[1];
  const float* in_b   = (const float*)d_in[2];
  const float* mo_w   = (const float*)d_in[3];
  const float* mo_b   = (const float*)d_in[4];
  const float* w_ih   = (const float*)d_in[5];
  const float* w_hh   = (const float*)d_in[6];
  const float* b_ih   = (const float*)d_in[7];
  const float* b_hh   = (const float*)d_in[8];
  const float* proj_w = (const float*)d_in[9];
  const float* proj_b = (const float*)d_in[10];
  uint8_t* ws = (uint8_t*)d_ws;
  int*            flagsIC = (int*)(ws + 0x0);
  int*            cnt     = (int*)(ws + 0x4000);
  float*          pooled  = (float*)(ws + 0x30000);
  unsigned short* wihbf   = (unsigned short*)(ws + 0x50000);
  int*            flr     = (int*)(ws + 0x300000);
  unsigned short* comb    = (unsigned short*)(ws + 0x800000);  // doubles as h-ring in k_lstm
  unsigned short* gates   = (unsigned short*)(ws + 0x3000000);
  unsigned short* qbuf    = (unsigned short*)(ws + 0x3000000); // aliases gates (dead before k_gates)
  unsigned short* kbuf    = (unsigned short*)(ws + 0x4000000);
  unsigned short* vbuf    = (unsigned short*)(ws + 0x5000000);
  unsigned short* ctx     = (unsigned short*)(ws + 0x6000000);

  hipMemsetAsync(ws + 0x300000, 0, 0x400000, stream);  // flr
  hipMemsetAsync(ws, 0, 0x4020, stream);               // flagsIC + cnt
  hipLaunchKernelGGL(k_convert, dim3(9216),    dim3(256), 0, stream, w_ih, x, wihbf, comb);
  hipLaunchKernelGGL(k_qkv,     dim3(12, 512), dim3(256), 0, stream, comb, in_w, in_b, qbuf, kbuf, vbuf);
  hipLaunchKernelGGL(k_attn,    dim3(512),     dim3(256), 0, stream, qbuf, kbuf, vbuf, ctx);
  hipLaunchKernelGGL(k_outproj, dim3(4, 512),  dim3(256), 0, stream, ctx, mo_w, mo_b, comb);
  hipLaunchKernelGGL(k_gates,   dim3(16, 256), dim3(256), 0, stream, comb, wihbf, b_ih, b_hh, gates);
  hipMemsetAsync(comb, 0, 0x10000, stream);  // h-ring slot 0 = h(-1) = zeros (comb dead now)
  hipLaunchKernelGGL(k_lstm,    dim3(512),     dim3(256), 0, stream, w_hh, gates, comb, pooled, flagsIC, flr, cnt);
  hipLaunchKernelGGL(k_final,   dim3(64),      dim3(256), 0, stream, pooled, proj_w, proj_b, (float*)d_out);
}

// Round 10
// 1153.058 us; speedup vs baseline: 3.4058x; 1.5388x over previous
//
#include <hip/hip_runtime.h>
#include <hip/hip_bf16.h>
#include <stdint.h>

// Problem: S=512, N=64, E=256, NH=8, HD=32, LH=512.
// Pipeline: convert -> qkv -> attn -> outproj -> gates GEMM -> persistent LSTM -> final proj.
// R16 = R15 + two changes:
//  - k_lstm: slot-major h-ring layout [st][g][slot][batch][u16]. Producer waves each
//    write ONE contiguous 128B L2 line (was 8 scattered 32B segments -> partial-line
//    write-through RMW); the per-step vmcnt(0) drain before the flag publish sits on the
//    critical path, so full-line writes should shorten it. Consumer fragment loads stay
//    16x b128 (unit u -> slot u>>4, offset u&15). The R10 synchronization schedule
//    (proven 1360us floor) is UNTOUCHED — indexing-only change.
//  - k_attn: 2 blocks per (n,h) (qt range split 0..7 / 8..15) -> 1024 blocks, 4/CU
//    (LDS 34.5KB x4 = 138KB < 160KB) for 2x latency-hiding TLP. K/V re-reads L2-resident.
// Kept from R15: k_gates m97-staging (global_load_lds 16B + both-sides XOR swizzle),
// vectorized-softmax k_attn body with P-writeback, R10-verbatim k_lstm handshake.

typedef __attribute__((ext_vector_type(8))) short bf16x8;
typedef __attribute__((ext_vector_type(4))) float f32x4;

__device__ __forceinline__ unsigned short f2bf(float f){
  unsigned u = __float_as_uint(f);
  u += 0x7FFFu + ((u >> 16) & 1u);          // RNE
  return (unsigned short)(u >> 16);
}
__device__ __forceinline__ float b2f(unsigned short h){
  return __uint_as_float(((unsigned)h) << 16);
}
__device__ __forceinline__ ushort4 f4tobf(float4 f){
  ushort4 o; o.x=f2bf(f.x); o.y=f2bf(f.y); o.z=f2bf(f.z); o.w=f2bf(f.w); return o;
}
// async global->LDS, 16B per lane: per-lane global src, wave-uniform LDS base (+lane*16).
__device__ __forceinline__ void gload_lds16(const void* g, void* l){
  __builtin_amdgcn_global_load_lds((const __attribute__((address_space(1))) unsigned int*)g,
                                   (__attribute__((address_space(3))) unsigned int*)l, 16, 0, 0);
}

// ---------------- workspace layout (bytes) ----------------
// flagsIC:  [0x0,      0x4000)   8 groups x 32 slots, 64B stride (IC fallback flags)
// cnt:      [0x4000,   0x4020)   8 ints, per-XCD slot claim
// pooled:   [0x30000,  0x50000)  64x512 f32
// w_ih bf16:[0x50000,  0x250000)
// flr:      [0x300000, 0x700000) replicated L2 flags: [st][r<8][g][slot] int, 4MB
// combined: [0x800000, 0x2800000) 32768x512 bf16; REUSED by k_lstm as h-ring:
//           ring[st][g][slot][batch][u16] = 8KB per (st,g); 64KB/step, 32MB total
// gates:    [0x3000000,0xB000000) layout [m][u][gate] = m*2048 + u*4 + gate (aliases q/k/v/ctx)
// q:0x3000000 k:0x4000000 v:0x5000000 ctx:0x6000000 (each 16MB bf16)
// total required ws: 0xB000000 = 184,549,376 B

// K0: w_ih fp32->bf16, and x fp32 -> combined[:, 0:256] bf16
__global__ __launch_bounds__(256) void k_convert(const float* __restrict__ wih,
                                                 const float* __restrict__ x,
                                                 unsigned short* __restrict__ wih_bf,
                                                 unsigned short* __restrict__ comb){
  size_t i = ((size_t)blockIdx.x * 256 + threadIdx.x) * 4;
  if (i < 1048576){
    float4 f = *(const float4*)(wih + i);
    *(ushort4*)(wih_bf + i) = f4tobf(f);
  } else {
    size_t j = i - 1048576;
    if (j < 8388608){
      float4 f = *(const float4*)(x + j);
      size_t m = j >> 8, c = j & 255;
      *(ushort4*)(comb + m*512 + c) = f4tobf(f);
    }
  }
}

// K1: qkv = x @ in_proj_w.T + b ; scale folded into q; writes q/k [n][h][s][d], v transposed [n][h][d][s]
__global__ __launch_bounds__(256) void k_qkv(const unsigned short* __restrict__ xb,
                                             const float* __restrict__ w,
                                             const float* __restrict__ bias,
                                             unsigned short* __restrict__ q,
                                             unsigned short* __restrict__ kk,
                                             unsigned short* __restrict__ v){
  const int nt = blockIdx.x;    // 0..11
  const int mt = blockIdx.y;    // 0..511  (= s, since M-row = s*64+n)
  __shared__ unsigned short Bs[64][264];
  const int t = threadIdx.x;
  { // stage+convert B tile (in_proj_w rows nt*64..+64, k 0..256)
    int row = t >> 2, c0 = (t & 3) * 64;
    const float* src = w + (size_t)(nt*64 + row)*256 + c0;
    #pragma unroll
    for (int i = 0; i < 64; i += 4){
      float4 f = *(const float4*)(src + i);
      *(ushort4*)&Bs[row][c0 + i] = f4tobf(f);
    }
  }
  __syncthreads();
  const int w4 = t >> 6, l = t & 63, lr = l & 15, lc = l >> 4;
  f32x4 acc[4];
  #pragma unroll
  for (int i = 0; i < 4; ++i) acc[i] = (f32x4){0.f,0.f,0.f,0.f};
  const size_t arow = (size_t)(mt*64 + w4*16 + lr) * 512;  // A from combined (bf16 x)
  #pragma unroll
  for (int kt = 0; kt < 8; ++kt){
    bf16x8 a = *(const bf16x8*)(xb + arow + kt*32 + lc*8);
    #pragma unroll
    for (int n4 = 0; n4 < 4; ++n4){
      bf16x8 b = *(const bf16x8*)&Bs[n4*16 + lr][kt*32 + lc*8];
      acc[n4] = __builtin_amdgcn_mfma_f32_16x16x32_bf16(a, b, acc[n4], 0, 0, 0);
    }
  }
  const int s = mt;
  #pragma unroll
  for (int n4 = 0; n4 < 4; ++n4){
    int ncol = nt*64 + n4*16 + lr;
    float bv = bias[ncol];
    int which = ncol >> 8, rem = ncol & 255, hh = rem >> 5, d = rem & 31;
    #pragma unroll
    for (int reg = 0; reg < 4; ++reg){
      int nb = w4*16 + lc*4 + reg;   // batch
      float val = acc[n4][reg] + bv;
      if (which == 0){
        val *= 0.17677669529663687f;  // 1/sqrt(32)
        q[((size_t)(nb*8 + hh)*512 + s)*32 + d] = f2bf(val);
      } else if (which == 1){
        kk[((size_t)(nb*8 + hh)*512 + s)*32 + d] = f2bf(val);
      } else {
        v[((size_t)(nb*8 + hh)*32 + d)*512 + s] = f2bf(val);
      }
    }
  }
}

// K2: attention; R16: 2 blocks per (n,h), each does 8 Q-tiles -> 1024 blocks, 4/CU.
// Vectorized softmax; P written back into sc (bit-identical); PV reads P directly.
__global__ __launch_bounds__(256) void k_attn(const unsigned short* __restrict__ q,
                                              const unsigned short* __restrict__ k,
                                              const unsigned short* __restrict__ v,
                                              unsigned short* __restrict__ ctx){
  const int bid = blockIdx.x;
  const int nh = bid >> 1, qh = bid & 1;
  const int n = nh >> 3, h = nh & 7;
  __shared__ unsigned short sc[32][520];
  __shared__ float red[32][8];
  __shared__ float rowinv[32];
  const unsigned short* qb = q + (size_t)nh * 512 * 32;
  const unsigned short* kb = k + (size_t)nh * 512 * 32;
  const unsigned short* vb = v + (size_t)nh * 32 * 512;
  const int t = threadIdx.x, w4 = t >> 6, l = t & 63, lr = l & 15, lc = l >> 4;
  const int r = t >> 3, cc = t & 7;
  for (int qt = qh*8; qt < qh*8 + 8; ++qt){
    const int s0 = qt * 32;
    bf16x8 aq0 = *(const bf16x8*)(qb + (size_t)(s0 + lr)*32 + lc*8);
    bf16x8 aq1 = *(const bf16x8*)(qb + (size_t)(s0 + 16 + lr)*32 + lc*8);
    #pragma unroll
    for (int j = 0; j < 8; ++j){
      int ntl = w4*8 + j;
      bf16x8 bk = *(const bf16x8*)(kb + (size_t)(ntl*16 + lr)*32 + lc*8);
      f32x4 d0 = (f32x4){0.f,0.f,0.f,0.f}, d1 = (f32x4){0.f,0.f,0.f,0.f};
      d0 = __builtin_amdgcn_mfma_f32_16x16x32_bf16(aq0, bk, d0, 0, 0, 0);
      d1 = __builtin_amdgcn_mfma_f32_16x16x32_bf16(aq1, bk, d1, 0, 0, 0);
      #pragma unroll
      for (int reg = 0; reg < 4; ++reg){
        sc[lc*4 + reg][ntl*16 + lr]      = f2bf(d0[reg]);
        sc[16 + lc*4 + reg][ntl*16 + lr] = f2bf(d1[reg]);
      }
    }
    __syncthreads();
    // max pass: thread (r,cc) owns chunks {i*8+cc} (8 x 8 cols, disjoint, b128 loads)
    float pm = -1e30f;
    #pragma unroll
    for (int i = 0; i < 8; ++i){
      bf16x8 vv = *(const bf16x8*)&sc[r][(i*8 + cc)*8];
      #pragma unroll
      for (int e = 0; e < 8; ++e) pm = fmaxf(pm, b2f((unsigned short)vv[e]));
    }
    red[r][cc] = pm;
    __syncthreads();
    float mfull = red[r][0];
    #pragma unroll
    for (int i = 1; i < 8; ++i) mfull = fmaxf(mfull, red[r][i]);
    __syncthreads();
    // sum pass + P writeback (same f32 exp and f2bf rounding -> bit-identical)
    float sum = 0.f;
    #pragma unroll
    for (int i = 0; i < 8; ++i){
      bf16x8 vv = *(const bf16x8*)&sc[r][(i*8 + cc)*8];
      bf16x8 pv;
      #pragma unroll
      for (int e = 0; e < 8; ++e){
        float p = __expf(b2f((unsigned short)vv[e]) - mfull);
        sum += p;
        pv[e] = (short)f2bf(p);
      }
      *(bf16x8*)&sc[r][(i*8 + cc)*8] = pv;
    }
    red[r][cc] = sum;
    __syncthreads();
    float ss = 0.f;
    #pragma unroll
    for (int i = 0; i < 8; ++i) ss += red[r][i];
    rowinv[r] = 1.f / ss;
    __syncthreads();
    // PV: each wave one 16x16 tile of the 32x32 O; A-frags = P directly from LDS
    const int mt = w4 >> 1, ntd = w4 & 1;
    const int arow = mt*16 + lr;
    f32x4 o = (f32x4){0.f,0.f,0.f,0.f};
    for (int kt = 0; kt < 16; ++kt){
      bf16x8 ap = *(const bf16x8*)&sc[arow][kt*32 + lc*8];
      bf16x8 bv = *(const bf16x8*)(vb + (size_t)(ntd*16 + lr)*512 + kt*32 + lc*8);
      o = __builtin_amdgcn_mfma_f32_16x16x32_bf16(ap, bv, o, 0, 0, 0);
    }
    #pragma unroll
    for (int reg = 0; reg < 4; ++reg){
      int row = mt*16 + lc*4 + reg;
      int d = ntd*16 + lr;
      float val = o[reg] * rowinv[row];
      ctx[((size_t)(s0 + row)*64 + n)*256 + h*32 + d] = f2bf(val);
    }
    __syncthreads();
  }
}

// K3: attn_out = ctx @ mha_out_w.T + b -> combined[:, 256:512]
__global__ __launch_bounds__(256) void k_outproj(const unsigned short* __restrict__ ctx,
                                                 const float* __restrict__ w,
                                                 const float* __restrict__ bias,
                                                 unsigned short* __restrict__ comb){
  const int nt = blockIdx.x;   // 0..3
  const int mt = blockIdx.y;   // 0..511
  __shared__ unsigned short Bs[64][264];
  const int t = threadIdx.x;
  {
    int row = t >> 2, c0 = (t & 3) * 64;
    const float* src = w + (size_t)(nt*64 + row)*256 + c0;
    #pragma unroll
    for (int i = 0; i < 64; i += 4){
      float4 f = *(const float4*)(src + i);
      *(ushort4*)&Bs[row][c0 + i] = f4tobf(f);
    }
  }
  __syncthreads();
  const int w4 = t >> 6, l = t & 63, lr = l & 15, lc = l >> 4;
  f32x4 acc[4];
  #pragma unroll
  for (int i = 0; i < 4; ++i) acc[i] = (f32x4){0.f,0.f,0.f,0.f};
  const size_t arow = (size_t)(mt*64 + w4*16 + lr) * 256;
  #pragma unroll
  for (int kt = 0; kt < 8; ++kt){
    bf16x8 a = *(const bf16x8*)(ctx + arow + kt*32 + lc*8);
    #pragma unroll
    for (int n4 = 0; n4 < 4; ++n4){
      bf16x8 b = *(const bf16x8*)&Bs[n4*16 + lr][kt*32 + lc*8];
      acc[n4] = __builtin_amdgcn_mfma_f32_16x16x32_bf16(a, b, acc[n4], 0, 0, 0);
    }
  }
  #pragma unroll
  for (int n4 = 0; n4 < 4; ++n4){
    int ncol = nt*64 + n4*16 + lr;
    float bv = bias[ncol];
    #pragma unroll
    for (int reg = 0; reg < 4; ++reg){
      int m = mt*64 + w4*16 + lc*4 + reg;
      comb[(size_t)m*512 + 256 + ncol] = f2bf(acc[n4][reg] + bv);
    }
  }
}

// K4: gates_x = combined @ w_ih.T + (b_ih + b_hh), 128x128 tiles, BK=64.
// m97-style staging (R15-proven): global_load_lds(16B) into linear [128][64] LDS; XOR
// chunk swizzle on GLOBAL source + LDS read. Output: gates[m][u][gate] = m*2048+u*4+gate.
__global__ __launch_bounds__(256) void k_gates(const unsigned short* __restrict__ A,
                                               const unsigned short* __restrict__ B,
                                               const float* __restrict__ bih,
                                               const float* __restrict__ bhh,
                                               unsigned short* __restrict__ gates){
  const int ntile = blockIdx.x;  // 0..15
  const int mtile = blockIdx.y;  // 0..255
  __shared__ unsigned short As[128][64], Bss[128][64];
  const int t = threadIdx.x, w4 = t >> 6, l = t & 63, lr = l & 15, lc = l >> 4;
  const int wm = w4 >> 1, wn = w4 & 1;
  f32x4 acc[4][4];
  #pragma unroll
  for (int i = 0; i < 4; ++i)
    #pragma unroll
    for (int j = 0; j < 4; ++j) acc[i][j] = (f32x4){0.f,0.f,0.f,0.f};
  const int ch = (l & 7) ^ (l >> 3);       // inverse-swizzled global chunk for this lane
  for (int kkk = 0; kkk < 8; ++kkk){
    #pragma unroll
    for (int c = 0; c < 4; ++c){
      const int row = w4*32 + c*8 + (l >> 3);
      gload_lds16(A + (size_t)(mtile*128 + row)*512 + kkk*64 + ch*8, &As [w4*32 + c*8][0]);
      gload_lds16(B + (size_t)(ntile*128 + row)*512 + kkk*64 + ch*8, &Bss[w4*32 + c*8][0]);
    }
    __syncthreads();   // compiler drains vmcnt before s_barrier -> LDS tiles complete
    #pragma unroll
    for (int kt = 0; kt < 2; ++kt){
      bf16x8 af[4], bfr[4];
      #pragma unroll
      for (int i = 0; i < 4; ++i)
        af[i]  = *(const bf16x8*)&As [wm*64 + i*16 + lr][(((kt*4 + lc) ^ (lr & 7)) * 8)];
      #pragma unroll
      for (int i = 0; i < 4; ++i)
        bfr[i] = *(const bf16x8*)&Bss[wn*64 + i*16 + lr][(((kt*4 + lc) ^ (lr & 7)) * 8)];
      #pragma unroll
      for (int i = 0; i < 4; ++i)
        #pragma unroll
        for (int j = 0; j < 4; ++j)
          acc[i][j] = __builtin_amdgcn_mfma_f32_16x16x32_bf16(af[i], bfr[j], acc[i][j], 0, 0, 0);
    }
    __syncthreads();
  }
  #pragma unroll
  for (int i = 0; i < 4; ++i){
    #pragma unroll
    for (int j = 0; j < 4; ++j){
      int ncol = ntile*128 + wn*64 + j*16 + lr;
      int gate = ncol >> 9, u = ncol & 511;
      float bsum = bih[ncol] + bhh[ncol];
      #pragma unroll
      for (int reg = 0; reg < 4; ++reg){
        int m = mtile*128 + wm*64 + i*16 + lc*4 + reg;
        gates[(size_t)m*2048 + u*4 + gate] = f2bf(acc[i][j][reg] + bsum);
      }
    }
  }
}

// K5: persistent LSTM, XCD-local — R10 schedule verbatim; R16: slot-major ring layout.
// ring[st][g] is an 8KB block organized [slot][batch][u16]: producer waves each write
// ONE contiguous 128B line (full-line write-through, no RMW); consumer loads unchanged
// width (16x b128). Handshake: replicated write-once L2 flags + IC fallback (proven).
__global__ __launch_bounds__(256, 1) void k_lstm(const float* __restrict__ whh,
                                                 const unsigned short* __restrict__ gates,
                                                 unsigned short* __restrict__ ring,
                                                 float* __restrict__ pooled,
                                                 int* __restrict__ flagsIC,
                                                 int* __restrict__ flr,
                                                 int* __restrict__ cnt){
  __shared__ unsigned short Wl[64][512];   // 64KB: rows = gate*16+unit
  __shared__ f32x4 Dg[4*2*16];             // 2KB:  [gate][lc][unit]
  __shared__ float padlds[5120];           // 20KB pad -> 86KB total -> 1 WG/CU
  __shared__ int s_hdr[2];
  const int t = threadIdx.x, w4 = t >> 6, l = t & 63, lr = l & 15, lc = l >> 4;
  if ((int)blockIdx.x == -1) ((volatile float*)padlds)[0] = 1.f;  // keep padlds
  if (t == 0){
    unsigned xcc;
    asm volatile("s_getreg_b32 %0, hwreg(HW_REG_XCC_ID)" : "=s"(xcc));
    int g = (int)(xcc & 7);
    s_hdr[0] = g;
    s_hdr[1] = atomicAdd(&cnt[g], 1);      // device-scope claim
  }
  __syncthreads();
  const int g = s_hdr[0], slot = s_hdr[1];
  if (slot >= 32) return;                  // spare WG: free the CU immediately
  const int j0 = slot * 16;
  { // stage w_hh slice fp32->bf16, chunk swizzle phys = logical ^ (row&7)
    const int row = t >> 2;
    const int gate = row >> 4, u = row & 15;
    const float* src = whh + (size_t)(gate*512 + j0 + u) * 512;
    const int cbase = (t & 3) * 16;
    #pragma unroll
    for (int i = 0; i < 16; ++i){
      const int lch = cbase + i;
      float4 f0 = *(const float4*)(src + lch*8);
      float4 f1 = *(const float4*)(src + lch*8 + 4);
      const int pch = lch ^ (row & 7);
      *(ushort4*)&Wl[row][pch*8]     = f4tobf(f0);
      *(ushort4*)&Wl[row][pch*8 + 4] = f4tobf(f1);
    }
  }
  const int eb = t >> 4, eu = t & 15;      // elementwise ownership, t<128: (batch, unit)
  float cst = 0.f, pool = 0.f;
  unsigned long long gx = 0, nx = 0;
  if (t < 128)
    gx = *(const unsigned long long*)(gates + (size_t)(g*8 + eb)*2048 + (j0 + eu)*4);
  int* const myflagIC = &flagsIC[(g*32 + slot)*16];
  __syncthreads();
  for (int st = 0; st < 512; ++st){
    if (st > 0){
      if (t < 32){
        // L2 fast poll: retry r reads replica r -> fresh L1 line every attempt ->
        // served by the local XCD L2 where peers' plain flag stores land.
        bool need = true;
        #pragma unroll 1
        for (int r = 0; r < 8 && need; ++r){
          int v = ((volatile const int*)flr)[((st*8 + r)*8 + g)*32 + (t & 31)];
          need = (bool)__any(v == 0);
        }
        if (need){
          // pathological skew: proven IC atomic poll (bounded, correct-by-delay)
          int* fp = &flagsIC[(g*32 + (t & 31))*16];
          int t2 = 0;
          while (__hip_atomic_load(fp, __ATOMIC_RELAXED, __HIP_MEMORY_SCOPE_AGENT) < st
                 && ++t2 < 5000) { }
        }
      }
      __syncthreads();
    }
    // h(st) @ Wl^T : A rows = 8 batches (lr&7, duplicated), wave w4 = gate w4.
    // slot-major ring: element (b, u) at base + (u>>4)*128 + b*16 + (u&15).
    // areg[kt] covers units kt*32+lc*8..+8 -> uslot = kt*2+(lc>>1), off = (lc&1)*8.
    const unsigned short* ha = ring + (((size_t)st*8 + g) << 12)
                               + (lc >> 1)*128 + (lr & 7)*16 + (lc & 1)*8;
    bf16x8 areg[16];
    #pragma unroll
    for (int kt = 0; kt < 16; ++kt) areg[kt] = *(const bf16x8*)(ha + kt*256);
    if (st < 511 && t < 128)
      nx = *(const unsigned long long*)(gates + ((size_t)(st+1)*64 + g*8 + eb)*2048 + (j0 + eu)*4);
    f32x4 acc0 = (f32x4){0.f,0.f,0.f,0.f}, acc1 = (f32x4){0.f,0.f,0.f,0.f};
    #pragma unroll
    for (int kt = 0; kt < 16; kt += 2){
      bf16x8 b0 = *(const bf16x8*)&Wl[w4*16 + lr][(((kt  )*4 + lc) ^ (lr & 7)) * 8];
      bf16x8 b1 = *(const bf16x8*)&Wl[w4*16 + lr][(((kt+1)*4 + lc) ^ (lr & 7)) * 8];
      acc0 = __builtin_amdgcn_mfma_f32_16x16x32_bf16(areg[kt],   b0, acc0, 0, 0, 0);
      acc1 = __builtin_amdgcn_mfma_f32_16x16x32_bf16(areg[kt+1], b1, acc1, 0, 0, 0);
    }
    f32x4 acc = acc0 + acc1;
    if (lc < 2) Dg[(w4*2 + lc)*16 + lr] = acc;   // D: col=unit(lane&15), row=batch(lc*4+reg)
    __syncthreads();
    if (t < 128){
      union { unsigned long long q; unsigned short u[4]; } ga; ga.q = gx;
      const int dq = (eb >> 2)*16 + eu, dr = eb & 3;
      float gi = Dg[0*32 + dq][dr] + b2f(ga.u[0]);
      float gf = Dg[1*32 + dq][dr] + b2f(ga.u[1]);
      float gc = Dg[2*32 + dq][dr] + b2f(ga.u[2]);
      float go = Dg[3*32 + dq][dr] + b2f(ga.u[3]);
      float i_ = __builtin_amdgcn_rcpf(1.f + __expf(-gi));
      float f_ = __builtin_amdgcn_rcpf(1.f + __expf(-gf));
      float cg = fminf(fmaxf(gc, -20.f), 20.f);
      float e2 = __expf(2.f * cg);
      float g_ = 1.f - 2.f * __builtin_amdgcn_rcpf(e2 + 1.f);
      float o_ = __builtin_amdgcn_rcpf(1.f + __expf(-go));
      float cn = f_ * cst + i_ * g_;
      cst = cn;
      float ct = fminf(fmaxf(cn, -20.f), 20.f);
      float e2c = __expf(2.f * ct);
      float th = 1.f - 2.f * __builtin_amdgcn_rcpf(e2c + 1.f);
      float hh = o_ * th;
      pool += hh;
      if (st < 511)  // slot-major: lanes t<128 write offsets slot*128+t -> each wave
                     // one contiguous 128B line, write-through to this XCD's L2
        ring[(((size_t)(st+1)*8 + g) << 12) + slot*128 + t] = f2bf(hh);
      gx = nx;
    }
    __syncthreads();   // pre-barrier vmcnt(0) drains h stores to L2 [m97-measured semantics]
    if (st < 511){
      // h(st+1) in L2 now. Notify: 8 write-once L2 replicas (flag-in-L2 => h-in-L2,
      // same cache) + 1 IC flag for the fallback path.
      if (t < 8) flr[(((st+1)*8 + t)*8 + g)*32 + slot] = 1;
      if (t == 0) __hip_atomic_store(myflagIC, st + 1, __ATOMIC_RELAXED, __HIP_MEMORY_SCOPE_AGENT);
    }
  }
  if (t < 128)
    pooled[(size_t)(g*8 + eb)*512 + j0 + eu] = pool * (1.f / 512.f);
}

// K6: out = log_sigmoid(pooled @ proj_w.T + proj_b)
__global__ __launch_bounds__(256) void k_final(const float* __restrict__ pooled,
                                               const float* __restrict__ w,
                                               const float* __restrict__ bias,
                                               float* __restrict__ out){
  const int n = blockIdx.x;
  __shared__ float pr[512];
  const int t = threadIdx.x;
  pr[t]       = pooled[(size_t)n*512 + t];
  pr[t + 256] = pooled[(size_t)n*512 + t + 256];
  __syncthreads();
  const float* wr = w + (size_t)t * 512;
  float s = bias[t];
  for (int i = 0; i < 512; i += 4){
    float4 f = *(const float4*)(wr + i);
    s += f.x*pr[i] + f.y*pr[i+1] + f.z*pr[i+2] + f.w*pr[i+3];
  }
  float rres = fminf(s, 0.f) - log1pf(__expf(-fabsf(s)));
  out[(size_t)n*256 + t] = rres;
}

extern "C" void kernel_launch(void* const* d_in, const int* in_sizes, int n_in,
                              void* d_out, int out_size, void* d_ws, size_t ws_size,
                              hipStream_t stream){
  const float* x      = (const float*)d_in[0];
  const float* in_w   = (const float*)d_in[1];
  const float* in_b   = (const float*)d_in[2];
  const float* mo_w   = (const float*)d_in[3];
  const float* mo_b   = (const float*)d_in[4];
  const float* w_ih   = (const float*)d_in[5];
  const float* w_hh   = (const float*)d_in[6];
  const float* b_ih   = (const float*)d_in[7];
  const float* b_hh   = (const float*)d_in[8];
  const float* proj_w = (const float*)d_in[9];
  const float* proj_b = (const float*)d_in[10];
  uint8_t* ws = (uint8_t*)d_ws;
  int*            flagsIC = (int*)(ws + 0x0);
  int*            cnt     = (int*)(ws + 0x4000);
  float*          pooled  = (float*)(ws + 0x30000);
  unsigned short* wihbf   = (unsigned short*)(ws + 0x50000);
  int*            flr     = (int*)(ws + 0x300000);
  unsigned short* comb    = (unsigned short*)(ws + 0x800000);  // doubles as h-ring in k_lstm
  unsigned short* gates   = (unsigned short*)(ws + 0x3000000);
  unsigned short* qbuf    = (unsigned short*)(ws + 0x3000000); // aliases gates (dead before k_gates)
  unsigned short* kbuf    = (unsigned short*)(ws + 0x4000000);
  unsigned short* vbuf    = (unsigned short*)(ws + 0x5000000);
  unsigned short* ctx     = (unsigned short*)(ws + 0x6000000);

  hipMemsetAsync(ws + 0x300000, 0, 0x400000, stream);  // flr
  hipMemsetAsync(ws, 0, 0x4020, stream);               // flagsIC + cnt
  hipLaunchKernelGGL(k_convert, dim3(9216),    dim3(256), 0, stream, w_ih, x, wihbf, comb);
  hipLaunchKernelGGL(k_qkv,     dim3(12, 512), dim3(256), 0, stream, comb, in_w, in_b, qbuf, kbuf, vbuf);
  hipLaunchKernelGGL(k_attn,    dim3(1024),    dim3(256), 0, stream, qbuf, kbuf, vbuf, ctx);
  hipLaunchKernelGGL(k_outproj, dim3(4, 512),  dim3(256), 0, stream, ctx, mo_w, mo_b, comb);
  hipLaunchKernelGGL(k_gates,   dim3(16, 256), dim3(256), 0, stream, comb, wihbf, b_ih, b_hh, gates);
  hipMemsetAsync(comb, 0, 0x10000, stream);  // h-ring slot 0 = h(-1) = zeros (comb dead now)
  hipLaunchKernelGGL(k_lstm,    dim3(512),     dim3(256), 0, stream, w_hh, gates, comb, pooled, flagsIC, flr, cnt);
  hipLaunchKernelGGL(k_final,   dim3(64),      dim3(256), 0, stream, pooled, proj_w, proj_b, (float*)d_out);
}